// Round 1
// baseline (874.709 us; speedup 1.0000x reference)
//
#include <hip/hip_runtime.h>
#include <hip/hip_bf16.h>

#define BATCH 2
#define S_LEN 2048
#define HID   4096
#define N_QKV 6144   // (32 + 2*8) * 128
#define NHEADS 32
#define NKVH   8
#define HDIM   128
#define MROWS  4096  // BATCH * S_LEN

typedef __attribute__((ext_vector_type(4))) float f32x4;
typedef __attribute__((ext_vector_type(8))) short bf16x8;
typedef __attribute__((ext_vector_type(4))) short bf16x4;

__device__ __forceinline__ unsigned short f2bf(float f) {
    unsigned int u = __float_as_uint(f);
    u += 0x7FFFu + ((u >> 16) & 1u);   // round-to-nearest-even
    return (unsigned short)(u >> 16);
}
__device__ __forceinline__ float bf2f(unsigned short v) {
    return __uint_as_float(((unsigned int)v) << 16);
}

// ---------------- 1. hidden fp32 -> bf16 ----------------
__global__ void cvt_bf16_kernel(const float* __restrict__ in, unsigned short* __restrict__ out) {
    size_t i = ((size_t)blockIdx.x * 256 + threadIdx.x) * 4;
    f32x4 v = *(const f32x4*)(in + i);
    bf16x4 o;
    o.x = (short)f2bf(v.x); o.y = (short)f2bf(v.y);
    o.z = (short)f2bf(v.z); o.w = (short)f2bf(v.w);
    *(bf16x4*)(out + i) = o;
}

// ---------------- 2. w_qkv (K x N fp32) -> w^T (N x K bf16) ----------------
__global__ void transpose_w_kernel(const float* __restrict__ w, unsigned short* __restrict__ wt) {
    __shared__ unsigned short tile[64][72];   // [k][n], padded
    const int tn = blockIdx.x * 64;
    const int tk = blockIdx.y * 64;
    const int t  = threadIdx.x;
    const int c4 = (t & 15) * 4;
    const int rr = t >> 4;                    // 0..15
#pragma unroll
    for (int i = 0; i < 4; i++) {
        int k = rr + i * 16;
        f32x4 v = *(const f32x4*)(w + (size_t)(tk + k) * N_QKV + tn + c4);
        tile[k][c4 + 0] = f2bf(v.x);
        tile[k][c4 + 1] = f2bf(v.y);
        tile[k][c4 + 2] = f2bf(v.z);
        tile[k][c4 + 3] = f2bf(v.w);
    }
    __syncthreads();
#pragma unroll
    for (int i = 0; i < 4; i++) {
        int n = rr + i * 16;
        bf16x4 o;
        o.x = (short)tile[c4 + 0][n];
        o.y = (short)tile[c4 + 1][n];
        o.z = (short)tile[c4 + 2][n];
        o.w = (short)tile[c4 + 3][n];
        *(bf16x4*)(wt + (size_t)(tn + n) * HID + tk + c4) = o;
    }
}

// ---------------- 3. bf16 GEMM: qkv[m][n] = A[m][k] * Bt[n][k]^T ----------------
__device__ __forceinline__ void gload_lds16(const unsigned short* g, unsigned short* l) {
    __builtin_amdgcn_global_load_lds(
        (const __attribute__((address_space(1))) unsigned int*)g,
        (__attribute__((address_space(3))) unsigned int*)l, 16, 0, 0);
}

__global__ __launch_bounds__(256) void gemm_qkv_kernel(const unsigned short* __restrict__ A,
                                                       const unsigned short* __restrict__ Bt,
                                                       unsigned short* __restrict__ C) {
    __shared__ unsigned short Al[128 * 32];
    __shared__ unsigned short Bl[128 * 32];
    const int bm = (blockIdx.x & 31) * 128;
    const int bn = (blockIdx.x >> 5) * 128;
    const int t = threadIdx.x;
    const int w = t >> 6, l = t & 63;
    const int wm = (w >> 1) * 64, wn = (w & 1) * 64;
    f32x4 acc[4][4] = {};

    // staging: wave w stages rows [w*32, w*32+32) of both tiles
    const int srow = w * 32 + (l >> 2);
    const int skk  = (l & 3) * 8;
    const unsigned short* ag = A  + (size_t)(bm + srow) * HID + skk;
    const unsigned short* bg = Bt + (size_t)(bn + srow) * HID + skk;

    for (int k0 = 0; k0 < HID; k0 += 32) {
#pragma unroll
        for (int c = 0; c < 2; c++) {
            gload_lds16(ag + (size_t)c * 16 * HID + k0, Al + (w * 32 + c * 16) * 32);
            gload_lds16(bg + (size_t)c * 16 * HID + k0, Bl + (w * 32 + c * 16) * 32);
        }
        __syncthreads();   // drains vmcnt before barrier
        bf16x8 af[4], bfr[4];
#pragma unroll
        for (int i = 0; i < 4; i++) {
            af[i]  = *(const bf16x8*)(Al + (wm + i * 16 + (l & 15)) * 32 + (l >> 4) * 8);
            bfr[i] = *(const bf16x8*)(Bl + (wn + i * 16 + (l & 15)) * 32 + (l >> 4) * 8);
        }
#pragma unroll
        for (int i = 0; i < 4; i++)
#pragma unroll
            for (int j = 0; j < 4; j++)
                acc[i][j] = __builtin_amdgcn_mfma_f32_16x16x32_bf16(af[i], bfr[j], acc[i][j], 0, 0, 0);
        __syncthreads();   // protect LDS before next stage
    }

#pragma unroll
    for (int i = 0; i < 4; i++)
#pragma unroll
        for (int j = 0; j < 4; j++)
#pragma unroll
            for (int r = 0; r < 4; r++) {
                int row = bm + wm + i * 16 + (l >> 4) * 4 + r;
                int col = bn + wn + j * 16 + (l & 15);
                C[(size_t)row * N_QKV + col] = f2bf(acc[i][j][r]);
            }
}

// ---------------- 4. RoPE in-place on Q/K regions (+ fold 1/sqrt(HD) into Q) ----------------
__global__ void rope_kernel(unsigned short* __restrict__ qkv,
                            const float* __restrict__ cs, const float* __restrict__ sn) {
    size_t id = (size_t)blockIdx.x * 256 + threadIdx.x;
    int d = (int)(id & 63);
    size_t tmp = id >> 6;
    int hd = (int)(tmp % 40);          // 0..31 = Q heads, 32..39 = K heads
    size_t r = tmp / 40;               // row = b*S + s
    float c = cs[r * HDIM + d];
    float s = sn[r * HDIM + d];
    unsigned short* p = qkv + r * N_QKV + (size_t)hd * HDIM + d;
    float x1 = bf2f(p[0]), x2 = bf2f(p[64]);
    float o1 = x1 * c - x2 * s;
    float o2 = x2 * c + x1 * s;
    if (hd < NHEADS) { o1 *= 0.088388347648318447f; o2 *= 0.088388347648318447f; }
    p[0]  = f2bf(o1);
    p[64] = f2bf(o2);
}

// ---------------- 5. causal GQA flash attention ----------------
__global__ __launch_bounds__(256) void attn_kernel(const unsigned short* __restrict__ qkv,
                                                   float* __restrict__ out) {
    __shared__ unsigned short Kl[32][136];    // K tile row-major, padded (kills D=128 bank conflict)
    __shared__ unsigned short Vt[128][40];    // V tile transposed [d][kv], padded (16B-aligned rows)
    __shared__ unsigned short Pl[4][16][48];  // per-wave P roundtrip, padded
    const int bid = blockIdx.x;
    const int qb  = (bid & 31) * 64;
    const int h   = (bid >> 5) & 31;
    const int b   = bid >> 10;
    const int kvh = h >> 2;                   // GROUPS = 4
    const int t = threadIdx.x, w = t >> 6, l = t & 63;
    const size_t rowb = (size_t)b * S_LEN;

    // Q fragments for this wave's 16 q-rows (already roped+scaled)
    bf16x8 qf[4];
    {
        int qrow = qb + w * 16 + (l & 15);
        const unsigned short* qp = qkv + (rowb + qrow) * N_QKV + (size_t)h * HDIM + (l >> 4) * 8;
#pragma unroll
        for (int kc = 0; kc < 4; kc++) qf[kc] = *(const bf16x8*)(qp + kc * 32);
    }

    f32x4 of[8] = {};
    float m_r[4], l_r[4];
#pragma unroll
    for (int r = 0; r < 4; r++) { m_r[r] = -1e30f; l_r[r] = 0.f; }

    const int ntiles = (qb + 64) >> 5;
    const int skv = t >> 3, sd = (t & 7) * 16;   // K staging: row kv, d-chunk
    const int vkv = t & 31, vd = (t >> 5) * 16;  // V staging: row kv, d-chunk

    for (int kt = 0; kt < ntiles; kt++) {
        const int kv0 = kt * 32;
        __syncthreads();
        {
            const unsigned short* kp = qkv + (rowb + kv0 + skv) * N_QKV + HID + (size_t)kvh * HDIM + sd;
            *(bf16x8*)(&Kl[skv][sd])     = *(const bf16x8*)(kp);
            *(bf16x8*)(&Kl[skv][sd + 8]) = *(const bf16x8*)(kp + 8);
            const unsigned short* vp = qkv + (rowb + kv0 + vkv) * N_QKV + HID + 1024 + (size_t)kvh * HDIM + vd;
            bf16x8 v0 = *(const bf16x8*)(vp);
            bf16x8 v1 = *(const bf16x8*)(vp + 8);
#pragma unroll
            for (int i = 0; i < 8; i++) Vt[vd + i][vkv]     = (unsigned short)v0[i];
#pragma unroll
            for (int i = 0; i < 8; i++) Vt[vd + 8 + i][vkv] = (unsigned short)v1[i];
        }
        __syncthreads();

        // S = Q * K^T  (16q x 32kv), scale pre-folded into Q
        f32x4 sf[2] = {};
#pragma unroll
        for (int kvb = 0; kvb < 2; kvb++)
#pragma unroll
            for (int kc = 0; kc < 4; kc++) {
                bf16x8 kf = *(const bf16x8*)(&Kl[kvb * 16 + (l & 15)][kc * 32 + (l >> 4) * 8]);
                sf[kvb] = __builtin_amdgcn_mfma_f32_16x16x32_bf16(qf[kc], kf, sf[kvb], 0, 0, 0);
            }

        // causal mask
        const int qg = qb + w * 16 + (l >> 4) * 4;
#pragma unroll
        for (int kvb = 0; kvb < 2; kvb++) {
            int kv = kv0 + kvb * 16 + (l & 15);
#pragma unroll
            for (int r = 0; r < 4; r++)
                if (kv > qg + r) sf[kvb][r] = -1e30f;
        }

        // online softmax (16-lane row groups)
        float pm[4], rs[4], sc[4];
#pragma unroll
        for (int r = 0; r < 4; r++) pm[r] = fmaxf(sf[0][r], sf[1][r]);
#pragma unroll
        for (int off = 8; off >= 1; off >>= 1)
#pragma unroll
            for (int r = 0; r < 4; r++) pm[r] = fmaxf(pm[r], __shfl_xor(pm[r], off, 64));
#pragma unroll
        for (int r = 0; r < 4; r++) {
            float mn = fmaxf(m_r[r], pm[r]);
            sc[r] = __expf(m_r[r] - mn);
            m_r[r] = mn;
            sf[0][r] = __expf(sf[0][r] - mn);
            sf[1][r] = __expf(sf[1][r] - mn);
            rs[r] = sf[0][r] + sf[1][r];
        }
#pragma unroll
        for (int off = 8; off >= 1; off >>= 1)
#pragma unroll
            for (int r = 0; r < 4; r++) rs[r] += __shfl_xor(rs[r], off, 64);
#pragma unroll
        for (int r = 0; r < 4; r++) l_r[r] = l_r[r] * sc[r] + rs[r];
#pragma unroll
        for (int i = 0; i < 8; i++)
#pragma unroll
            for (int r = 0; r < 4; r++) of[i][r] *= sc[r];

        // P -> LDS (C-layout) -> read back in A-layout
#pragma unroll
        for (int kvb = 0; kvb < 2; kvb++)
#pragma unroll
            for (int r = 0; r < 4; r++)
                Pl[w][(l >> 4) * 4 + r][kvb * 16 + (l & 15)] = f2bf(sf[kvb][r]);
        bf16x8 pf = *(const bf16x8*)(&Pl[w][l & 15][(l >> 4) * 8]);

        // O += P * V
#pragma unroll
        for (int d16 = 0; d16 < 8; d16++) {
            bf16x8 vf = *(const bf16x8*)(&Vt[d16 * 16 + (l & 15)][(l >> 4) * 8]);
            of[d16] = __builtin_amdgcn_mfma_f32_16x16x32_bf16(pf, vf, of[d16], 0, 0, 0);
        }
    }

    const int qg = qb + w * 16 + (l >> 4) * 4;
#pragma unroll
    for (int d16 = 0; d16 < 8; d16++)
#pragma unroll
        for (int r = 0; r < 4; r++)
            out[(rowb + qg + r) * HID + (size_t)h * HDIM + d16 * 16 + (l & 15)] = of[d16][r] / l_r[r];
}

extern "C" void kernel_launch(void* const* d_in, const int* in_sizes, int n_in,
                              void* d_out, int out_size, void* d_ws, size_t ws_size,
                              hipStream_t stream) {
    const float* hidden = (const float*)d_in[0];
    const float* cosb   = (const float*)d_in[1];
    const float* sinb   = (const float*)d_in[2];
    const float* w_qkv  = (const float*)d_in[3];
    // d_in[4] = position_ids (unused; cos/sin already positional)

    unsigned short* hbf = (unsigned short*)d_ws;                   // 32 MB
    unsigned short* wt  = hbf + (size_t)MROWS * HID;               // 48 MB
    unsigned short* qkv = wt + (size_t)N_QKV * HID;                // 48 MB
    float* out = (float*)d_out;

    cvt_bf16_kernel<<<(MROWS * (size_t)HID) / 1024, 256, 0, stream>>>(hidden, hbf);
    transpose_w_kernel<<<dim3(N_QKV / 64, HID / 64), 256, 0, stream>>>(w_qkv, wt);
    gemm_qkv_kernel<<<(MROWS / 128) * (N_QKV / 128), 256, 0, stream>>>(hbf, wt, qkv);
    rope_kernel<<<((size_t)MROWS * 40 * 64) / 256, 256, 0, stream>>>(qkv, cosb, sinb);
    attn_kernel<<<BATCH * NHEADS * (S_LEN / 64), 256, 0, stream>>>(qkv, out);
}

// Round 2
// 711.272 us; speedup vs baseline: 1.2298x; 1.2298x over previous
//
#include <hip/hip_runtime.h>
#include <hip/hip_bf16.h>

#define BATCH 2
#define S_LEN 2048
#define HID   4096
#define N_QKV 6144   // (32 + 2*8) * 128
#define NHEADS 32
#define NKVH   8
#define HDIM   128
#define MROWS  4096  // BATCH * S_LEN
#define QBLK  128
#define KVBLK 64

typedef __attribute__((ext_vector_type(4))) float f32x4;
typedef __attribute__((ext_vector_type(8))) short bf16x8;
typedef __attribute__((ext_vector_type(4))) short bf16x4;

__device__ __forceinline__ unsigned short f2bf(float f) {
    unsigned int u = __float_as_uint(f);
    u += 0x7FFFu + ((u >> 16) & 1u);   // round-to-nearest-even
    return (unsigned short)(u >> 16);
}
__device__ __forceinline__ float bf2f(unsigned short v) {
    return __uint_as_float(((unsigned int)v) << 16);
}

// ---------------- 1. hidden fp32 -> bf16 ----------------
__global__ void cvt_bf16_kernel(const float* __restrict__ in, unsigned short* __restrict__ out) {
    size_t i = ((size_t)blockIdx.x * 256 + threadIdx.x) * 4;
    f32x4 v = *(const f32x4*)(in + i);
    bf16x4 o;
    o.x = (short)f2bf(v.x); o.y = (short)f2bf(v.y);
    o.z = (short)f2bf(v.z); o.w = (short)f2bf(v.w);
    *(bf16x4*)(out + i) = o;
}

// ---------------- 2. w_qkv (K x N fp32) -> w^T (N x K bf16) ----------------
__global__ void transpose_w_kernel(const float* __restrict__ w, unsigned short* __restrict__ wt) {
    __shared__ unsigned short tile[64][72];   // [k][n], padded
    const int tn = blockIdx.x * 64;
    const int tk = blockIdx.y * 64;
    const int t  = threadIdx.x;
    const int c4 = (t & 15) * 4;
    const int rr = t >> 4;                    // 0..15
#pragma unroll
    for (int i = 0; i < 4; i++) {
        int k = rr + i * 16;
        f32x4 v = *(const f32x4*)(w + (size_t)(tk + k) * N_QKV + tn + c4);
        tile[k][c4 + 0] = f2bf(v.x);
        tile[k][c4 + 1] = f2bf(v.y);
        tile[k][c4 + 2] = f2bf(v.z);
        tile[k][c4 + 3] = f2bf(v.w);
    }
    __syncthreads();
#pragma unroll
    for (int i = 0; i < 4; i++) {
        int n = rr + i * 16;
        bf16x4 o;
        o.x = (short)tile[c4 + 0][n];
        o.y = (short)tile[c4 + 1][n];
        o.z = (short)tile[c4 + 2][n];
        o.w = (short)tile[c4 + 3][n];
        *(bf16x4*)(wt + (size_t)(tn + n) * HID + tk + c4) = o;
    }
}

// ---------------- async global -> LDS ----------------
__device__ __forceinline__ void gload_lds16(const unsigned short* g, unsigned short* l) {
    __builtin_amdgcn_global_load_lds(
        (const __attribute__((address_space(1))) unsigned int*)g,
        (__attribute__((address_space(3))) unsigned int*)l, 16, 0, 0);
}

// ---------------- 3. bf16 GEMM: qkv[m][n] = A[m][k] * Bt[n][k]^T ----------------
__global__ __launch_bounds__(256) void gemm_qkv_kernel(const unsigned short* __restrict__ A,
                                                       const unsigned short* __restrict__ Bt,
                                                       unsigned short* __restrict__ C) {
    __shared__ unsigned short Al[128 * 32];
    __shared__ unsigned short Bl[128 * 32];
    const int bm = (blockIdx.x & 31) * 128;
    const int bn = (blockIdx.x >> 5) * 128;
    const int t = threadIdx.x;
    const int w = t >> 6, l = t & 63;
    const int wm = (w >> 1) * 64, wn = (w & 1) * 64;
    f32x4 acc[4][4] = {};

    const int srow = w * 32 + (l >> 2);
    const int skk  = (l & 3) * 8;
    const unsigned short* ag = A  + (size_t)(bm + srow) * HID + skk;
    const unsigned short* bg = Bt + (size_t)(bn + srow) * HID + skk;

    for (int k0 = 0; k0 < HID; k0 += 32) {
#pragma unroll
        for (int c = 0; c < 2; c++) {
            gload_lds16(ag + (size_t)c * 16 * HID + k0, Al + (w * 32 + c * 16) * 32);
            gload_lds16(bg + (size_t)c * 16 * HID + k0, Bl + (w * 32 + c * 16) * 32);
        }
        __syncthreads();
        bf16x8 af[4], bfr[4];
#pragma unroll
        for (int i = 0; i < 4; i++) {
            af[i]  = *(const bf16x8*)(Al + (wm + i * 16 + (l & 15)) * 32 + (l >> 4) * 8);
            bfr[i] = *(const bf16x8*)(Bl + (wn + i * 16 + (l & 15)) * 32 + (l >> 4) * 8);
        }
#pragma unroll
        for (int i = 0; i < 4; i++)
#pragma unroll
            for (int j = 0; j < 4; j++)
                acc[i][j] = __builtin_amdgcn_mfma_f32_16x16x32_bf16(af[i], bfr[j], acc[i][j], 0, 0, 0);
        __syncthreads();
    }

#pragma unroll
    for (int i = 0; i < 4; i++)
#pragma unroll
        for (int j = 0; j < 4; j++)
#pragma unroll
            for (int r = 0; r < 4; r++) {
                int row = bm + wm + i * 16 + (l >> 4) * 4 + r;
                int col = bn + wn + j * 16 + (l & 15);
                C[(size_t)row * N_QKV + col] = f2bf(acc[i][j][r]);
            }
}

// ---------------- 4. RoPE in-place on Q/K regions (+ fold 1/sqrt(HD) into Q) ----------------
__global__ void rope_kernel(unsigned short* __restrict__ qkv,
                            const float* __restrict__ cs, const float* __restrict__ sn) {
    size_t id = (size_t)blockIdx.x * 256 + threadIdx.x;
    int d = (int)(id & 63);
    size_t tmp = id >> 6;
    int hd = (int)(tmp % 40);          // 0..31 = Q heads, 32..39 = K heads
    size_t r = tmp / 40;               // row = b*S + s
    float c = cs[r * HDIM + d];
    float s = sn[r * HDIM + d];
    unsigned short* p = qkv + r * N_QKV + (size_t)hd * HDIM + d;
    float x1 = bf2f(p[0]), x2 = bf2f(p[64]);
    float o1 = x1 * c - x2 * s;
    float o2 = x2 * c + x1 * s;
    if (hd < NHEADS) { o1 *= 0.088388347648318447f; o2 *= 0.088388347648318447f; }
    p[0]  = f2bf(o1);
    p[64] = f2bf(o2);
}

// ---------------- 4b. V transpose: qkv V region -> vtg[b][kvh][d][s] ----------------
__global__ void transpose_v_kernel(const unsigned short* __restrict__ qkv,
                                   unsigned short* __restrict__ vtg) {
    __shared__ unsigned short tile[64][72];
    const int bz = blockIdx.z;               // b*8 + kvh
    const int d0 = blockIdx.y * 64;
    const int s0 = blockIdx.x * 64;
    const int b  = bz >> 3, kvh = bz & 7;
    const int t = threadIdx.x;
#pragma unroll
    for (int i = 0; i < 2; i++) {
        int s  = i * 32 + (t >> 3);
        int dl = (t & 7) * 8;
        bf16x8 v = *(const bf16x8*)(qkv + (size_t)(b * S_LEN + s0 + s) * N_QKV
                                    + HID + NKVH * HDIM + (size_t)kvh * HDIM + d0 + dl);
        *(bf16x8*)(&tile[s][dl]) = v;
    }
    __syncthreads();
#pragma unroll
    for (int i = 0; i < 2; i++) {
        int d  = i * 32 + (t >> 3);
        int sl = (t & 7) * 8;
        bf16x8 o;
#pragma unroll
        for (int j = 0; j < 8; j++) o[j] = (short)tile[sl + j][d];
        *(bf16x8*)(vtg + ((size_t)bz * HDIM + d0 + d) * S_LEN + s0 + sl) = o;
    }
}

// ---------------- 5. causal GQA flash attention (QBLK=128, KVBLK=64) ----------------
__global__ __launch_bounds__(256, 2) void attn_kernel(const unsigned short* __restrict__ qkv,
                                                      const unsigned short* __restrict__ vtg,
                                                      float* __restrict__ out) {
    __shared__ unsigned short Kl[2][KVBLK * HDIM];   // double-buffered, chunk-swizzled
    __shared__ unsigned short Vl[HDIM * KVBLK];      // V^T [d][kv], chunk-swizzled
    __shared__ unsigned short Pl[4][16 * 72];        // per-wave P roundtrip

    const int bid = blockIdx.x;
    const int qbi = bid & 15;
    const int h   = (bid >> 4) & 31;
    const int b   = bid >> 9;
    const int kvh = h >> 2;                           // GROUPS = 4
    const int qb  = qbi * QBLK;
    const int t = threadIdx.x, w = t >> 6, l = t & 63;
    const int lo = l & 15, hi = l >> 4;
    const int sw = lo & 7;
    const size_t rowb = (size_t)b * S_LEN;

    // staging source pointers with XOR chunk-swizzle baked into the global address
    const int krow = t >> 4;                          // + 16*i
    const unsigned short* kg = qkv + (rowb + krow) * N_QKV + HID + (size_t)kvh * HDIM
                               + (((t & 15) ^ (krow & 7)) << 3);
    const int vrow = t >> 3;                          // + 32*i
    const unsigned short* vg = vtg + ((size_t)(b * NKVH + kvh) * HDIM + vrow) * S_LEN
                               + (((t & 7) ^ (vrow & 7)) << 3);
    unsigned short* kl0 = &Kl[0][t * 8];
    unsigned short* kl1 = &Kl[1][t * 8];
    unsigned short* vl  = &Vl[t * 8];

    // Q fragments (post-RoPE, scale folded): 2 q-groups x 4 k-chunks
    bf16x8 qf[2][4];
#pragma unroll
    for (int g = 0; g < 2; g++) {
        const unsigned short* qp = qkv + (rowb + qb + w * 32 + g * 16 + lo) * N_QKV
                                   + (size_t)h * HDIM + hi * 8;
#pragma unroll
        for (int kc = 0; kc < 4; kc++) qf[g][kc] = *(const bf16x8*)(qp + kc * 32);
    }

    f32x4 of[2][8] = {};
    float m_r[2][4], l_r[2][4];
#pragma unroll
    for (int g = 0; g < 2; g++)
#pragma unroll
        for (int r = 0; r < 4; r++) { m_r[g][r] = -1e30f; l_r[g][r] = 0.f; }

    const int nt = (qb + QBLK) / KVBLK;
    const int wrowmax = qb + w * 32 + 31;

    // prologue: stage K tile 0
#pragma unroll
    for (int i = 0; i < 4; i++)
        gload_lds16(kg + (size_t)i * 16 * N_QKV, kl0 + i * 2048);

    for (int kt = 0; kt < nt; kt++) {
        const int kv0 = kt * KVBLK;
        __syncthreads();                              // K(kt) landed; Vl reads from kt-1 done
        // stage V(kt) (consumed after mid barrier)
#pragma unroll
        for (int i = 0; i < 4; i++)
            gload_lds16(vg + kv0 + (size_t)i * 32 * S_LEN, vl + i * 2048);
        // prefetch K(kt+1)
        if (kt + 1 < nt) {
            const unsigned short* kp = kg + (size_t)(kv0 + KVBLK) * N_QKV;
            unsigned short* kd = ((kt + 1) & 1) ? kl1 : kl0;
#pragma unroll
            for (int i = 0; i < 4; i++)
                gload_lds16(kp + (size_t)i * 16 * N_QKV, kd + i * 2048);
        }

        bf16x8 pf[2][2];
        const bool wact = (kv0 <= wrowmax);
        if (wact) {
            const unsigned short* Kb = (kt & 1) ? &Kl[1][0] : &Kl[0][0];
            // S = Q K^T : 2 qg x 64 kv
            f32x4 sf[2][4] = {};
#pragma unroll
            for (int kvb = 0; kvb < 4; kvb++)
#pragma unroll
                for (int kc = 0; kc < 4; kc++) {
                    bf16x8 kf = *(const bf16x8*)(Kb + (kvb * 16 + lo) * HDIM
                                                 + (((kc * 4 + hi) ^ sw) << 3));
#pragma unroll
                    for (int g = 0; g < 2; g++)
                        sf[g][kvb] = __builtin_amdgcn_mfma_f32_16x16x32_bf16(
                            qf[g][kc], kf, sf[g][kvb], 0, 0, 0);
                }
#pragma unroll
            for (int g = 0; g < 2; g++) {
                const int rb = qb + w * 32 + g * 16;
                if (kv0 + KVBLK - 1 > rb) {           // causal mask needed
#pragma unroll
                    for (int kvb = 0; kvb < 4; kvb++) {
                        const int kv = kv0 + kvb * 16 + lo;
#pragma unroll
                        for (int r = 0; r < 4; r++)
                            if (kv > rb + hi * 4 + r) sf[g][kvb][r] = -1e30f;
                    }
                }
                // online softmax: rows are (hi*4+r), reduce across the 16 `lo` lanes
                float pm[4];
#pragma unroll
                for (int r = 0; r < 4; r++)
                    pm[r] = fmaxf(fmaxf(sf[g][0][r], sf[g][1][r]),
                                  fmaxf(sf[g][2][r], sf[g][3][r]));
#pragma unroll
                for (int off = 8; off >= 1; off >>= 1)
#pragma unroll
                    for (int r = 0; r < 4; r++)
                        pm[r] = fmaxf(pm[r], __shfl_xor(pm[r], off, 64));
                // defer-max (T13): skip rescale unless max grew by > 8
                float dm = fmaxf(fmaxf(pm[0] - m_r[g][0], pm[1] - m_r[g][1]),
                                 fmaxf(pm[2] - m_r[g][2], pm[3] - m_r[g][3]));
                if (__any(dm > 8.0f)) {
#pragma unroll
                    for (int r = 0; r < 4; r++) {
                        const float mn = fmaxf(m_r[g][r], pm[r]);
                        const float sc = __expf(m_r[g][r] - mn);
                        m_r[g][r] = mn;
                        l_r[g][r] *= sc;
#pragma unroll
                        for (int d16 = 0; d16 < 8; d16++) of[g][d16][r] *= sc;
                    }
                }
                float rs[4] = {0.f, 0.f, 0.f, 0.f};
#pragma unroll
                for (int kvb = 0; kvb < 4; kvb++)
#pragma unroll
                    for (int r = 0; r < 4; r++) {
                        const float p = __expf(sf[g][kvb][r] - m_r[g][r]);
                        sf[g][kvb][r] = p;
                        rs[r] += p;
                    }
#pragma unroll
                for (int off = 8; off >= 1; off >>= 1)
#pragma unroll
                    for (int r = 0; r < 4; r++) rs[r] += __shfl_xor(rs[r], off, 64);
#pragma unroll
                for (int r = 0; r < 4; r++) l_r[g][r] += rs[r];
                // P -> LDS (C layout) -> A-fragments (wave-private, lgkm-ordered)
                unsigned short* Pw = &Pl[w][0];
#pragma unroll
                for (int kvb = 0; kvb < 4; kvb++)
#pragma unroll
                    for (int r = 0; r < 4; r++)
                        Pw[(hi * 4 + r) * 72 + kvb * 16 + lo] = f2bf(sf[g][kvb][r]);
#pragma unroll
                for (int kh = 0; kh < 2; kh++)
                    pf[g][kh] = *(const bf16x8*)(Pw + lo * 72 + kh * 32 + hi * 8);
            }
        }
        __syncthreads();                              // V(kt) landed (vmcnt drained)
        if (wact) {
#pragma unroll
            for (int kh = 0; kh < 2; kh++)
#pragma unroll
                for (int d16 = 0; d16 < 8; d16++) {
                    bf16x8 vf = *(const bf16x8*)(&Vl[0]
                                                 + ((d16 * 16 + lo) << 6)
                                                 + (((kh * 4 + hi) ^ sw) << 3));
#pragma unroll
                    for (int g = 0; g < 2; g++)
                        of[g][d16] = __builtin_amdgcn_mfma_f32_16x16x32_bf16(
                            pf[g][kh], vf, of[g][d16], 0, 0, 0);
                }
        }
    }

    // epilogue: normalize and store
#pragma unroll
    for (int g = 0; g < 2; g++) {
        float inv[4];
#pragma unroll
        for (int r = 0; r < 4; r++) inv[r] = 1.0f / l_r[g][r];
        const size_t rb = rowb + qb + w * 32 + g * 16 + hi * 4;
#pragma unroll
        for (int d16 = 0; d16 < 8; d16++)
#pragma unroll
            for (int r = 0; r < 4; r++)
                out[(rb + r) * HID + (size_t)h * HDIM + d16 * 16 + lo] = of[g][d16][r] * inv[r];
    }
}

extern "C" void kernel_launch(void* const* d_in, const int* in_sizes, int n_in,
                              void* d_out, int out_size, void* d_ws, size_t ws_size,
                              hipStream_t stream) {
    const float* hidden = (const float*)d_in[0];
    const float* cosb   = (const float*)d_in[1];
    const float* sinb   = (const float*)d_in[2];
    const float* w_qkv  = (const float*)d_in[3];

    unsigned short* hbf = (unsigned short*)d_ws;                   // 32 MiB (dead after GEMM)
    unsigned short* wt  = hbf + (size_t)MROWS * HID;               // 48 MiB
    unsigned short* qkv = wt + (size_t)N_QKV * HID;                // 48 MiB
    unsigned short* vtg = (unsigned short*)d_ws;                   // 8 MiB, overlaps hbf (post-GEMM)
    float* out = (float*)d_out;

    cvt_bf16_kernel<<<(MROWS * (size_t)HID) / 1024, 256, 0, stream>>>(hidden, hbf);
    transpose_w_kernel<<<dim3(N_QKV / 64, HID / 64), 256, 0, stream>>>(w_qkv, wt);
    gemm_qkv_kernel<<<(MROWS / 128) * (N_QKV / 128), 256, 0, stream>>>(hbf, wt, qkv);
    rope_kernel<<<((size_t)MROWS * 40 * 64) / 256, 256, 0, stream>>>(qkv, cosb, sinb);
    transpose_v_kernel<<<dim3(S_LEN / 64, HDIM / 64, BATCH * NKVH), 256, 0, stream>>>(qkv, vtg);
    attn_kernel<<<BATCH * NHEADS * (S_LEN / QBLK), 256, 0, stream>>>(qkv, vtg, out);
}

// Round 3
// 661.845 us; speedup vs baseline: 1.3216x; 1.0747x over previous
//
#include <hip/hip_runtime.h>
#include <hip/hip_bf16.h>

#define BATCH 2
#define S_LEN 2048
#define HID   4096
#define N_QKV 6144   // (32 + 2*8) * 128
#define NHEADS 32
#define NKVH   8
#define HDIM   128
#define MROWS  4096  // BATCH * S_LEN
#define QBLK  128
#define KVBLK 64
#define NT_K  64     // 4096 / 64 K-tiles for the GEMM

typedef __attribute__((ext_vector_type(4))) float f32x4;
typedef __attribute__((ext_vector_type(8))) short bf16x8;
typedef __attribute__((ext_vector_type(4))) short bf16x4;

__device__ __forceinline__ unsigned short f2bf(float f) {
    unsigned int u = __float_as_uint(f);
    u += 0x7FFFu + ((u >> 16) & 1u);   // round-to-nearest-even
    return (unsigned short)(u >> 16);
}
__device__ __forceinline__ float bf2f(unsigned short v) {
    return __uint_as_float(((unsigned int)v) << 16);
}

// ---------------- 1. hidden fp32 -> bf16 ----------------
__global__ void cvt_bf16_kernel(const float* __restrict__ in, unsigned short* __restrict__ out) {
    size_t i = ((size_t)blockIdx.x * 256 + threadIdx.x) * 4;
    f32x4 v = *(const f32x4*)(in + i);
    bf16x4 o;
    o.x = (short)f2bf(v.x); o.y = (short)f2bf(v.y);
    o.z = (short)f2bf(v.z); o.w = (short)f2bf(v.w);
    *(bf16x4*)(out + i) = o;
}

// ---------------- 2. w_qkv (K x N fp32) -> w^T (N x K bf16) ----------------
__global__ void transpose_w_kernel(const float* __restrict__ w, unsigned short* __restrict__ wt) {
    __shared__ unsigned short tile[64][72];   // [k][n], padded
    const int tn = blockIdx.x * 64;
    const int tk = blockIdx.y * 64;
    const int t  = threadIdx.x;
    const int c4 = (t & 15) * 4;
    const int rr = t >> 4;                    // 0..15
#pragma unroll
    for (int i = 0; i < 4; i++) {
        int k = rr + i * 16;
        f32x4 v = *(const f32x4*)(w + (size_t)(tk + k) * N_QKV + tn + c4);
        tile[k][c4 + 0] = f2bf(v.x);
        tile[k][c4 + 1] = f2bf(v.y);
        tile[k][c4 + 2] = f2bf(v.z);
        tile[k][c4 + 3] = f2bf(v.w);
    }
    __syncthreads();
#pragma unroll
    for (int i = 0; i < 4; i++) {
        int n = rr + i * 16;
        bf16x4 o;
        o.x = (short)tile[c4 + 0][n];
        o.y = (short)tile[c4 + 1][n];
        o.z = (short)tile[c4 + 2][n];
        o.w = (short)tile[c4 + 3][n];
        *(bf16x4*)(wt + (size_t)(tn + n) * HID + tk + c4) = o;
    }
}

// ---------------- async global -> LDS ----------------
__device__ __forceinline__ void gload_lds16(const unsigned short* g, unsigned short* l) {
    __builtin_amdgcn_global_load_lds(
        (const __attribute__((address_space(1))) unsigned int*)g,
        (__attribute__((address_space(3))) unsigned int*)l, 16, 0, 0);
}

// ---------------- 3. bf16 GEMM, 256x256 tile, BK=64, 8-phase counted-vmcnt ----------------
// LDS per operand: [2 dbuf][2 khalf][256 rows][32 k] bf16, 16B-chunk XOR swizzle
// chunk_sw = chunk ^ ((row>>1)&3)  (inverse baked into global staging address)
__global__ __launch_bounds__(512, 2) void gemm_qkv_kernel(const unsigned short* __restrict__ A,
                                                          const unsigned short* __restrict__ Bt,
                                                          unsigned short* __restrict__ C) {
    __shared__ alignas(16) unsigned short AL[32768];   // 64 KiB
    __shared__ alignas(16) unsigned short BL[32768];   // 64 KiB
    const int t = threadIdx.x;            // 0..511
    const int w = t >> 6, l = t & 63;
    const int lo = l & 15, hi = l >> 4;
    const int wr = w >> 2, wc = w & 3;    // wave tile: 128x64 at (wr*128, wc*64)
    // XCD-aware bijective swizzle: 384 blocks = 8 XCD * 48
    const int bid = blockIdx.x;
    const int swz = (bid & 7) * 48 + (bid >> 3);
    const int bm = (swz / 24) * 256;
    const int bn = (swz % 24) * 256;

    // staging per-thread constants (pre-swizzled global source, linear LDS dest)
    const int rS = t >> 2;                              // row 0..127 (+128*iss)
    const int cS = (t & 3) ^ ((rS >> 1) & 3);           // logical 16B chunk
    const unsigned short* As = A  + (size_t)(bm + rS) * HID + cS * 8;
    const unsigned short* Bs = Bt + (size_t)(bn + rS) * HID + cS * 8;
    unsigned short* ALd = AL + t * 8;
    unsigned short* BLd = BL + t * 8;

#define STAGE_A(DST, KPOS) do { \
        gload_lds16(As + (KPOS), ALd + (DST)); \
        gload_lds16(As + (size_t)128 * HID + (KPOS), ALd + (DST) + 4096); } while (0)
#define STAGE_B(DST, KPOS) do { \
        gload_lds16(Bs + (KPOS), BLd + (DST)); \
        gload_lds16(Bs + (size_t)128 * HID + (KPOS), BLd + (DST) + 4096); } while (0)

    // prologue: tile0 (all 4 halves) + tile1 k0 halves  -> 12 loads in flight
    STAGE_A(0, 0);            STAGE_B(0, 0);            // (0,A,k0) (0,B,k0)
    STAGE_A(8192, 32);        STAGE_B(8192, 32);        // (0,A,k1) (0,B,k1)
    STAGE_A(16384, 64);       STAGE_B(16384, 64);       // (1,A,k0) (1,B,k0)
    asm volatile("s_waitcnt vmcnt(8)" ::: "memory");    // oldest 2 halves landed
    __builtin_amdgcn_s_barrier();

    f32x4 acc[8][4] = {};
    const int csw8 = (hi ^ ((l & 6) >> 1)) * 8;         // swizzled chunk offset (ushorts)

#define GPHASE(KHB, MH, READB, STAGECODE, WAITCODE) do {                         \
        bf16x8 af0, af1, af2, af3;                                               \
        { const unsigned short* ap = Ab + (KHB) + (wr * 128 + (MH) * 64 + lo) * 32 + csw8; \
          af0 = *(const bf16x8*)(ap);                                            \
          af1 = *(const bf16x8*)(ap + 16 * 32);                                  \
          af2 = *(const bf16x8*)(ap + 32 * 32);                                  \
          af3 = *(const bf16x8*)(ap + 48 * 32); }                                \
        if (READB) {                                                             \
          const unsigned short* bp = Bb + (KHB) + (wc * 64 + lo) * 32 + csw8;    \
          bfr[0] = *(const bf16x8*)(bp);                                         \
          bfr[1] = *(const bf16x8*)(bp + 16 * 32);                               \
          bfr[2] = *(const bf16x8*)(bp + 32 * 32);                               \
          bfr[3] = *(const bf16x8*)(bp + 48 * 32); }                             \
        STAGECODE;                                                               \
        __builtin_amdgcn_s_barrier();                                            \
        __builtin_amdgcn_s_setprio(1);                                           \
        _Pragma("unroll")                                                        \
        for (int jj = 0; jj < 4; jj++) {                                         \
            acc[(MH)*4+0][jj] = __builtin_amdgcn_mfma_f32_16x16x32_bf16(af0, bfr[jj], acc[(MH)*4+0][jj], 0, 0, 0); \
            acc[(MH)*4+1][jj] = __builtin_amdgcn_mfma_f32_16x16x32_bf16(af1, bfr[jj], acc[(MH)*4+1][jj], 0, 0, 0); \
            acc[(MH)*4+2][jj] = __builtin_amdgcn_mfma_f32_16x16x32_bf16(af2, bfr[jj], acc[(MH)*4+2][jj], 0, 0, 0); \
            acc[(MH)*4+3][jj] = __builtin_amdgcn_mfma_f32_16x16x32_bf16(af3, bfr[jj], acc[(MH)*4+3][jj], 0, 0, 0); \
        }                                                                        \
        __builtin_amdgcn_s_setprio(0);                                           \
        WAITCODE;                                                                \
        __builtin_amdgcn_s_barrier();                                            \
    } while (0)

    for (int u = 0; u < NT_K; u++) {
        const int buf = (u & 1) * 16384;
        const unsigned short* Ab = AL + buf;
        const unsigned short* Bb = BL + buf;
        bf16x8 bfr[4];
        // P1: kh0, mh0 | prefetch (u+1, A, k1)
        GPHASE(0, 0, 1,
               { if (u + 1 < NT_K) STAGE_A(((u + 1) & 1) * 16384 + 8192, (u + 1) * 64 + 32); },
               {});
        // P2: kh0, mh1 | prefetch (u+1, B, k1) | wait for (u,*,k1)
        GPHASE(0, 1, 0,
               { if (u + 1 < NT_K) STAGE_B(((u + 1) & 1) * 16384 + 8192, (u + 1) * 64 + 32); },
               { if (u < NT_K - 1) asm volatile("s_waitcnt vmcnt(8)" ::: "memory");
                 else              asm volatile("s_waitcnt vmcnt(0)" ::: "memory"); });
        // P3: kh1, mh0 | prefetch (u+2, A, k0)
        GPHASE(8192, 0, 1,
               { if (u + 2 < NT_K) STAGE_A(buf, (u + 2) * 64); },
               {});
        // P4: kh1, mh1 | prefetch (u+2, B, k0) | wait for (u+1,*,k0)
        GPHASE(8192, 1, 0,
               { if (u + 2 < NT_K) STAGE_B(buf, (u + 2) * 64); },
               { if (u < NT_K - 2)      asm volatile("s_waitcnt vmcnt(8)" ::: "memory");
                 else if (u == NT_K - 2) asm volatile("s_waitcnt vmcnt(4)" ::: "memory"); });
    }
#undef GPHASE
#undef STAGE_A
#undef STAGE_B

#pragma unroll
    for (int i = 0; i < 8; i++)
#pragma unroll
        for (int j = 0; j < 4; j++)
#pragma unroll
            for (int r = 0; r < 4; r++) {
                const int row = bm + wr * 128 + i * 16 + hi * 4 + r;
                const int col = bn + wc * 64 + j * 16 + lo;
                C[(size_t)row * N_QKV + col] = f2bf(acc[i][j][r]);
            }
}

// ---------------- 4. RoPE in-place on Q/K regions (+ fold 1/sqrt(HD) into Q) ----------------
__global__ void rope_kernel(unsigned short* __restrict__ qkv,
                            const float* __restrict__ cs, const float* __restrict__ sn) {
    size_t id = (size_t)blockIdx.x * 256 + threadIdx.x;
    int d = (int)(id & 63);
    size_t tmp = id >> 6;
    int hd = (int)(tmp % 40);          // 0..31 = Q heads, 32..39 = K heads
    size_t r = tmp / 40;               // row = b*S + s
    float c = cs[r * HDIM + d];
    float s = sn[r * HDIM + d];
    unsigned short* p = qkv + r * N_QKV + (size_t)hd * HDIM + d;
    float x1 = bf2f(p[0]), x2 = bf2f(p[64]);
    float o1 = x1 * c - x2 * s;
    float o2 = x2 * c + x1 * s;
    if (hd < NHEADS) { o1 *= 0.088388347648318447f; o2 *= 0.088388347648318447f; }
    p[0]  = f2bf(o1);
    p[64] = f2bf(o2);
}

// ---------------- 4b. V transpose: qkv V region -> vtg[b][kvh][d][s] ----------------
__global__ void transpose_v_kernel(const unsigned short* __restrict__ qkv,
                                   unsigned short* __restrict__ vtg) {
    __shared__ unsigned short tile[64][72];
    const int bz = blockIdx.z;               // b*8 + kvh
    const int d0 = blockIdx.y * 64;
    const int s0 = blockIdx.x * 64;
    const int b  = bz >> 3, kvh = bz & 7;
    const int t = threadIdx.x;
#pragma unroll
    for (int i = 0; i < 2; i++) {
        int s  = i * 32 + (t >> 3);
        int dl = (t & 7) * 8;
        bf16x8 v = *(const bf16x8*)(qkv + (size_t)(b * S_LEN + s0 + s) * N_QKV
                                    + HID + NKVH * HDIM + (size_t)kvh * HDIM + d0 + dl);
        *(bf16x8*)(&tile[s][dl]) = v;
    }
    __syncthreads();
#pragma unroll
    for (int i = 0; i < 2; i++) {
        int d  = i * 32 + (t >> 3);
        int sl = (t & 7) * 8;
        bf16x8 o;
#pragma unroll
        for (int j = 0; j < 8; j++) o[j] = (short)tile[sl + j][d];
        *(bf16x8*)(vtg + ((size_t)bz * HDIM + d0 + d) * S_LEN + s0 + sl) = o;
    }
}

// ---------------- 5. causal GQA flash attention (paired q-blocks for balance) ----------------
__global__ __launch_bounds__(256, 2) void attn_kernel(const unsigned short* __restrict__ qkv,
                                                      const unsigned short* __restrict__ vtg,
                                                      float* __restrict__ out) {
    __shared__ unsigned short Kl[2][KVBLK * HDIM];   // double-buffered, chunk-swizzled
    __shared__ unsigned short Vl[HDIM * KVBLK];      // V^T [d][kv], chunk-swizzled
    __shared__ unsigned short Pl[4][16 * 72];        // per-wave P roundtrip

    const int bid = blockIdx.x;
    const int qbi0 = bid & 7;
    const int h   = (bid >> 3) & 31;
    const int b   = bid >> 8;
    const int kvh = h >> 2;                           // GROUPS = 4
    const int t = threadIdx.x, w = t >> 6, l = t & 63;
    const int lo = l & 15, hi = l >> 4;
    const int sw = lo & 7;
    const size_t rowb = (size_t)b * S_LEN;

    const int krow = t >> 4;
    const unsigned short* kg = qkv + (rowb + krow) * N_QKV + HID + (size_t)kvh * HDIM
                               + (((t & 15) ^ (krow & 7)) << 3);
    const int vrow = t >> 3;
    const unsigned short* vg = vtg + ((size_t)(b * NKVH + kvh) * HDIM + vrow) * S_LEN
                               + (((t & 7) ^ (vrow & 7)) << 3);
    unsigned short* kl0 = &Kl[0][t * 8];
    unsigned short* kl1 = &Kl[1][t * 8];
    unsigned short* vl  = &Vl[t * 8];

    for (int hv = 0; hv < 2; hv++) {
        const int qb = (hv ? (15 - qbi0) : qbi0) * QBLK;

        // Q fragments (post-RoPE, scale folded): 2 q-groups x 4 k-chunks
        bf16x8 qf[2][4];
#pragma unroll
        for (int g = 0; g < 2; g++) {
            const unsigned short* qp = qkv + (rowb + qb + w * 32 + g * 16 + lo) * N_QKV
                                       + (size_t)h * HDIM + hi * 8;
#pragma unroll
            for (int kc = 0; kc < 4; kc++) qf[g][kc] = *(const bf16x8*)(qp + kc * 32);
        }

        f32x4 of[2][8] = {};
        float m_r[2][4], l_r[2][4];
#pragma unroll
        for (int g = 0; g < 2; g++)
#pragma unroll
            for (int r = 0; r < 4; r++) { m_r[g][r] = -1e30f; l_r[g][r] = 0.f; }

        const int nt = (qb + QBLK) / KVBLK;          // always even
        const int wrowmax = qb + w * 32 + 31;

        // prologue: stage K tile 0 (into Kl[0]; prior half ended reading Kl[1])
#pragma unroll
        for (int i = 0; i < 4; i++)
            gload_lds16(kg + (size_t)i * 16 * N_QKV, kl0 + i * 2048);

        for (int kt = 0; kt < nt; kt++) {
            const int kv0 = kt * KVBLK;
            __syncthreads();                          // K(kt) landed; prior Vl reads done
#pragma unroll
            for (int i = 0; i < 4; i++)
                gload_lds16(vg + kv0 + (size_t)i * 32 * S_LEN, vl + i * 2048);
            if (kt + 1 < nt) {
                const unsigned short* kp = kg + (size_t)(kv0 + KVBLK) * N_QKV;
                unsigned short* kd = ((kt + 1) & 1) ? kl1 : kl0;
#pragma unroll
                for (int i = 0; i < 4; i++)
                    gload_lds16(kp + (size_t)i * 16 * N_QKV, kd + i * 2048);
            }

            bf16x8 pf[2][2];
            const bool wact = (kv0 <= wrowmax);
            if (wact) {
                const unsigned short* Kb = (kt & 1) ? &Kl[1][0] : &Kl[0][0];
                f32x4 sf[2][4] = {};
#pragma unroll
                for (int kvb = 0; kvb < 4; kvb++)
#pragma unroll
                    for (int kc = 0; kc < 4; kc++) {
                        bf16x8 kf = *(const bf16x8*)(Kb + (kvb * 16 + lo) * HDIM
                                                     + (((kc * 4 + hi) ^ sw) << 3));
#pragma unroll
                        for (int g = 0; g < 2; g++)
                            sf[g][kvb] = __builtin_amdgcn_mfma_f32_16x16x32_bf16(
                                qf[g][kc], kf, sf[g][kvb], 0, 0, 0);
                    }
#pragma unroll
                for (int g = 0; g < 2; g++) {
                    const int rb = qb + w * 32 + g * 16;
                    if (kv0 + KVBLK - 1 > rb) {
#pragma unroll
                        for (int kvb = 0; kvb < 4; kvb++) {
                            const int kv = kv0 + kvb * 16 + lo;
#pragma unroll
                            for (int r = 0; r < 4; r++)
                                if (kv > rb + hi * 4 + r) sf[g][kvb][r] = -1e30f;
                        }
                    }
                    float pm[4];
#pragma unroll
                    for (int r = 0; r < 4; r++)
                        pm[r] = fmaxf(fmaxf(sf[g][0][r], sf[g][1][r]),
                                      fmaxf(sf[g][2][r], sf[g][3][r]));
#pragma unroll
                    for (int off = 8; off >= 1; off >>= 1)
#pragma unroll
                        for (int r = 0; r < 4; r++)
                            pm[r] = fmaxf(pm[r], __shfl_xor(pm[r], off, 64));
                    float dm = fmaxf(fmaxf(pm[0] - m_r[g][0], pm[1] - m_r[g][1]),
                                     fmaxf(pm[2] - m_r[g][2], pm[3] - m_r[g][3]));
                    if (__any(dm > 8.0f)) {
#pragma unroll
                        for (int r = 0; r < 4; r++) {
                            const float mn = fmaxf(m_r[g][r], pm[r]);
                            const float sc = __expf(m_r[g][r] - mn);
                            m_r[g][r] = mn;
                            l_r[g][r] *= sc;
#pragma unroll
                            for (int d16 = 0; d16 < 8; d16++) of[g][d16][r] *= sc;
                        }
                    }
                    float rs[4] = {0.f, 0.f, 0.f, 0.f};
#pragma unroll
                    for (int kvb = 0; kvb < 4; kvb++)
#pragma unroll
                        for (int r = 0; r < 4; r++) {
                            const float p = __expf(sf[g][kvb][r] - m_r[g][r]);
                            sf[g][kvb][r] = p;
                            rs[r] += p;
                        }
#pragma unroll
                    for (int off = 8; off >= 1; off >>= 1)
#pragma unroll
                        for (int r = 0; r < 4; r++) rs[r] += __shfl_xor(rs[r], off, 64);
#pragma unroll
                    for (int r = 0; r < 4; r++) l_r[g][r] += rs[r];
                    unsigned short* Pw = &Pl[w][0];
#pragma unroll
                    for (int kvb = 0; kvb < 4; kvb++)
#pragma unroll
                        for (int r = 0; r < 4; r++)
                            Pw[(hi * 4 + r) * 72 + kvb * 16 + lo] = f2bf(sf[g][kvb][r]);
#pragma unroll
                    for (int kh = 0; kh < 2; kh++)
                        pf[g][kh] = *(const bf16x8*)(Pw + lo * 72 + kh * 32 + hi * 8);
                }
            }
            __syncthreads();                          // V(kt) landed
            if (wact) {
#pragma unroll
                for (int kh = 0; kh < 2; kh++)
#pragma unroll
                    for (int d16 = 0; d16 < 8; d16++) {
                        bf16x8 vf = *(const bf16x8*)(&Vl[0]
                                                     + ((d16 * 16 + lo) << 6)
                                                     + (((kh * 4 + hi) ^ sw) << 3));
#pragma unroll
                        for (int g = 0; g < 2; g++)
                            of[g][d16] = __builtin_amdgcn_mfma_f32_16x16x32_bf16(
                                pf[g][kh], vf, of[g][d16], 0, 0, 0);
                    }
            }
        }

#pragma unroll
        for (int g = 0; g < 2; g++) {
            float inv[4];
#pragma unroll
            for (int r = 0; r < 4; r++) inv[r] = 1.0f / l_r[g][r];
            const size_t rb = rowb + qb + w * 32 + g * 16 + hi * 4;
#pragma unroll
            for (int d16 = 0; d16 < 8; d16++)
#pragma unroll
                for (int r = 0; r < 4; r++)
                    out[(rb + r) * HID + (size_t)h * HDIM + d16 * 16 + lo] = of[g][d16][r] * inv[r];
        }
    }
}

extern "C" void kernel_launch(void* const* d_in, const int* in_sizes, int n_in,
                              void* d_out, int out_size, void* d_ws, size_t ws_size,
                              hipStream_t stream) {
    const float* hidden = (const float*)d_in[0];
    const float* cosb   = (const float*)d_in[1];
    const float* sinb   = (const float*)d_in[2];
    const float* w_qkv  = (const float*)d_in[3];

    unsigned short* hbf = (unsigned short*)d_ws;                   // 32 MiB (dead after GEMM)
    unsigned short* wt  = hbf + (size_t)MROWS * HID;               // 48 MiB
    unsigned short* qkv = wt + (size_t)N_QKV * HID;                // 48 MiB
    unsigned short* vtg = (unsigned short*)d_ws;                   // 8 MiB, overlaps hbf (post-GEMM)
    float* out = (float*)d_out;

    cvt_bf16_kernel<<<(MROWS * (size_t)HID) / 1024, 256, 0, stream>>>(hidden, hbf);
    transpose_w_kernel<<<dim3(N_QKV / 64, HID / 64), 256, 0, stream>>>(w_qkv, wt);
    gemm_qkv_kernel<<<(MROWS / 256) * (N_QKV / 256), 512, 0, stream>>>(hbf, wt, qkv);
    rope_kernel<<<((size_t)MROWS * 40 * 64) / 256, 256, 0, stream>>>(qkv, cosb, sinb);
    transpose_v_kernel<<<dim3(S_LEN / 64, HDIM / 64, BATCH * NKVH), 256, 0, stream>>>(qkv, vtg);
    attn_kernel<<<BATCH * NHEADS * (S_LEN / QBLK / 2), 256, 0, stream>>>(qkv, vtg, out);
}

// Round 4
// 608.756 us; speedup vs baseline: 1.4369x; 1.0872x over previous
//
#include <hip/hip_runtime.h>
#include <hip/hip_bf16.h>

#define BATCH 2
#define S_LEN 2048
#define HID   4096
#define N_QKV 6144   // (32 + 2*8) * 128
#define NHEADS 32
#define NKVH   8
#define HDIM   128
#define MROWS  4096  // BATCH * S_LEN
#define QBLK  128
#define KVBLK 64
#define NT_K  64     // 4096 / 64 K-tiles for the GEMM

typedef __attribute__((ext_vector_type(4))) float f32x4;
typedef __attribute__((ext_vector_type(8))) short bf16x8;
typedef __attribute__((ext_vector_type(4))) short bf16x4;

__device__ __forceinline__ unsigned short f2bf(float f) {
    unsigned int u = __float_as_uint(f);
    u += 0x7FFFu + ((u >> 16) & 1u);   // round-to-nearest-even
    return (unsigned short)(u >> 16);
}
__device__ __forceinline__ float bf2f(unsigned short v) {
    return __uint_as_float(((unsigned int)v) << 16);
}

// ---------------- 1. hidden fp32 -> bf16 ----------------
__global__ void cvt_bf16_kernel(const float* __restrict__ in, unsigned short* __restrict__ out) {
    size_t i = ((size_t)blockIdx.x * 256 + threadIdx.x) * 4;
    f32x4 v = *(const f32x4*)(in + i);
    bf16x4 o;
    o.x = (short)f2bf(v.x); o.y = (short)f2bf(v.y);
    o.z = (short)f2bf(v.z); o.w = (short)f2bf(v.w);
    *(bf16x4*)(out + i) = o;
}

// ---------------- 2. w_qkv (K x N fp32) -> w^T (N x K bf16) ----------------
__global__ void transpose_w_kernel(const float* __restrict__ w, unsigned short* __restrict__ wt) {
    __shared__ unsigned short tile[64][72];   // [k][n], padded
    const int tn = blockIdx.x * 64;
    const int tk = blockIdx.y * 64;
    const int t  = threadIdx.x;
    const int c4 = (t & 15) * 4;
    const int rr = t >> 4;                    // 0..15
#pragma unroll
    for (int i = 0; i < 4; i++) {
        int k = rr + i * 16;
        f32x4 v = *(const f32x4*)(w + (size_t)(tk + k) * N_QKV + tn + c4);
        tile[k][c4 + 0] = f2bf(v.x);
        tile[k][c4 + 1] = f2bf(v.y);
        tile[k][c4 + 2] = f2bf(v.z);
        tile[k][c4 + 3] = f2bf(v.w);
    }
    __syncthreads();
#pragma unroll
    for (int i = 0; i < 4; i++) {
        int n = rr + i * 16;
        bf16x4 o;
        o.x = (short)tile[c4 + 0][n];
        o.y = (short)tile[c4 + 1][n];
        o.z = (short)tile[c4 + 2][n];
        o.w = (short)tile[c4 + 3][n];
        *(bf16x4*)(wt + (size_t)(tn + n) * HID + tk + c4) = o;
    }
}

// ---------------- async global -> LDS ----------------
__device__ __forceinline__ void gload_lds16(const unsigned short* g, unsigned short* l) {
    __builtin_amdgcn_global_load_lds(
        (const __attribute__((address_space(1))) unsigned int*)g,
        (__attribute__((address_space(3))) unsigned int*)l, 16, 0, 0);
}

// ---------------- 3. bf16 GEMM, 128x256 tile, BK=64, counted-vmcnt phases ----------------
// grid = 32 x 24 = 768 blocks = exactly 3 full rounds of 256 CUs (no partial-round idle).
// LDS: AL [2 dbuf][2 kh][128][32], BL [2 dbuf][2 kh][256][32]; 16B-chunk XOR swizzle
// chunk_sw = chunk ^ ((row>>1)&3), inverse baked into the global staging address.
__global__ __launch_bounds__(512, 2) void gemm_qkv_kernel(const unsigned short* __restrict__ A,
                                                          const unsigned short* __restrict__ Bt,
                                                          unsigned short* __restrict__ C) {
    __shared__ alignas(16) unsigned short AL[16384];   // 32 KiB
    __shared__ alignas(16) unsigned short BL[32768];   // 64 KiB
    const int t = threadIdx.x;            // 0..511
    const int w = t >> 6, l = t & 63;
    const int lo = l & 15, hi = l >> 4;
    const int wr = w >> 2, wc = w & 3;    // wave tile 64x64 at (wr*64, wc*64)
    // XCD-grouped, column-major tile order: each XCD owns 3 contiguous bn-columns,
    // sweeping bm within a column (2 MB B-panel stays hot in that XCD's L2).
    const int bid = blockIdx.x;
    const int g = (bid & 7) * 96 + (bid >> 3);         // bijective, 768 = 8*96
    const int bm = (g & 31) * 128;
    const int bn = (g >> 5) * 256;

    const int rS = t >> 2;                              // staging row 0..127
    const int cS = (t & 3) ^ ((rS >> 1) & 3);           // logical 16B chunk (pre-swizzled)
    const unsigned short* As = A  + (size_t)(bm + rS) * HID + cS * 8;
    const unsigned short* Bs = Bt + (size_t)(bn + rS) * HID + cS * 8;

#define STAGE_A(DB, KH, KPOS) gload_lds16(As + (KPOS), AL + (DB) * 8192 + (KH) * 4096 + t * 8)
#define STAGE_B(DB, KH, KPOS) do { \
        gload_lds16(Bs + (KPOS), BL + (DB) * 16384 + (KH) * 8192 + t * 8); \
        gload_lds16(Bs + (size_t)128 * HID + (KPOS), BL + (DB) * 16384 + (KH) * 8192 + 4096 + t * 8); } while (0)

    // prologue: T0.k0, T0.k1, T1.k0  (3+3+3 = 9 loads/thread in flight)
    STAGE_A(0, 0, 0);   STAGE_B(0, 0, 0);
    STAGE_A(0, 1, 32);  STAGE_B(0, 1, 32);
    STAGE_A(1, 0, 64);  STAGE_B(1, 0, 64);
    asm volatile("s_waitcnt vmcnt(6)" ::: "memory");    // T0.k0 landed
    __builtin_amdgcn_s_barrier();

    f32x4 acc[4][4] = {};
    const int csw8 = (hi ^ ((l & 6) >> 1)) * 8;         // swizzled chunk offset (ushorts)

#define GPHASE(U, KH, STAGECODE, WAITCODE) do {                                  \
        const unsigned short* ap = AL + ((U) & 1) * 8192 + (KH) * 4096           \
                                   + (wr * 64 + lo) * 32 + csw8;                 \
        const unsigned short* bp = BL + ((U) & 1) * 16384 + (KH) * 8192          \
                                   + (wc * 64 + lo) * 32 + csw8;                 \
        bf16x8 af0 = *(const bf16x8*)(ap);                                       \
        bf16x8 af1 = *(const bf16x8*)(ap + 512);                                 \
        bf16x8 af2 = *(const bf16x8*)(ap + 1024);                                \
        bf16x8 af3 = *(const bf16x8*)(ap + 1536);                                \
        bf16x8 bf0 = *(const bf16x8*)(bp);                                       \
        bf16x8 bf1 = *(const bf16x8*)(bp + 512);                                 \
        bf16x8 bf2 = *(const bf16x8*)(bp + 1024);                                \
        bf16x8 bf3 = *(const bf16x8*)(bp + 1536);                                \
        STAGECODE;                                                               \
        __builtin_amdgcn_s_barrier();                                            \
        __builtin_amdgcn_s_setprio(1);                                           \
        acc[0][0] = __builtin_amdgcn_mfma_f32_16x16x32_bf16(af0, bf0, acc[0][0], 0, 0, 0); \
        acc[0][1] = __builtin_amdgcn_mfma_f32_16x16x32_bf16(af0, bf1, acc[0][1], 0, 0, 0); \
        acc[0][2] = __builtin_amdgcn_mfma_f32_16x16x32_bf16(af0, bf2, acc[0][2], 0, 0, 0); \
        acc[0][3] = __builtin_amdgcn_mfma_f32_16x16x32_bf16(af0, bf3, acc[0][3], 0, 0, 0); \
        acc[1][0] = __builtin_amdgcn_mfma_f32_16x16x32_bf16(af1, bf0, acc[1][0], 0, 0, 0); \
        acc[1][1] = __builtin_amdgcn_mfma_f32_16x16x32_bf16(af1, bf1, acc[1][1], 0, 0, 0); \
        acc[1][2] = __builtin_amdgcn_mfma_f32_16x16x32_bf16(af1, bf2, acc[1][2], 0, 0, 0); \
        acc[1][3] = __builtin_amdgcn_mfma_f32_16x16x32_bf16(af1, bf3, acc[1][3], 0, 0, 0); \
        acc[2][0] = __builtin_amdgcn_mfma_f32_16x16x32_bf16(af2, bf0, acc[2][0], 0, 0, 0); \
        acc[2][1] = __builtin_amdgcn_mfma_f32_16x16x32_bf16(af2, bf1, acc[2][1], 0, 0, 0); \
        acc[2][2] = __builtin_amdgcn_mfma_f32_16x16x32_bf16(af2, bf2, acc[2][2], 0, 0, 0); \
        acc[2][3] = __builtin_amdgcn_mfma_f32_16x16x32_bf16(af2, bf3, acc[2][3], 0, 0, 0); \
        acc[3][0] = __builtin_amdgcn_mfma_f32_16x16x32_bf16(af3, bf0, acc[3][0], 0, 0, 0); \
        acc[3][1] = __builtin_amdgcn_mfma_f32_16x16x32_bf16(af3, bf1, acc[3][1], 0, 0, 0); \
        acc[3][2] = __builtin_amdgcn_mfma_f32_16x16x32_bf16(af3, bf2, acc[3][2], 0, 0, 0); \
        acc[3][3] = __builtin_amdgcn_mfma_f32_16x16x32_bf16(af3, bf3, acc[3][3], 0, 0, 0); \
        __builtin_amdgcn_s_setprio(0);                                           \
        WAITCODE;                                                                \
        __builtin_amdgcn_s_barrier();                                            \
    } while (0)

    // In-flight ledger (3 loads per staged half-group, in-order completion):
    //  entry tile u: {T(u).k1, T(u+1).k0} = 6 outstanding
    //  P1: +T(u+1).k1 -> 9; wait 6 drains T(u).k1
    //  P2: +T(u+2).k0 -> 9; wait 6 drains T(u+1).k0
    for (int u = 0; u < NT_K; u++) {
        GPHASE(u, 0,
               { if (u + 1 < NT_K) { STAGE_A((u + 1) & 1, 1, (u + 1) * 64 + 32);
                                     STAGE_B((u + 1) & 1, 1, (u + 1) * 64 + 32); } },
               { if (u < NT_K - 1) asm volatile("s_waitcnt vmcnt(6)" ::: "memory");
                 else              asm volatile("s_waitcnt vmcnt(0)" ::: "memory"); });
        GPHASE(u, 1,
               { if (u + 2 < NT_K) { STAGE_A(u & 1, 0, (u + 2) * 64);
                                     STAGE_B(u & 1, 0, (u + 2) * 64); } },
               { if (u < NT_K - 2)       asm volatile("s_waitcnt vmcnt(6)" ::: "memory");
                 else if (u == NT_K - 2) asm volatile("s_waitcnt vmcnt(3)" ::: "memory"); });
    }
#undef GPHASE
#undef STAGE_A
#undef STAGE_B

#pragma unroll
    for (int i = 0; i < 4; i++)
#pragma unroll
        for (int j = 0; j < 4; j++)
#pragma unroll
            for (int r = 0; r < 4; r++) {
                const int row = bm + wr * 64 + i * 16 + hi * 4 + r;
                const int col = bn + wc * 64 + j * 16 + lo;
                C[(size_t)row * N_QKV + col] = f2bf(acc[i][j][r]);
            }
}

// ---------------- 4. RoPE in-place on Q/K regions (+ fold 1/sqrt(HD) into Q) ----------------
__global__ void rope_kernel(unsigned short* __restrict__ qkv,
                            const float* __restrict__ cs, const float* __restrict__ sn) {
    size_t id = (size_t)blockIdx.x * 256 + threadIdx.x;
    int d = (int)(id & 63);
    size_t tmp = id >> 6;
    int hd = (int)(tmp % 40);          // 0..31 = Q heads, 32..39 = K heads
    size_t r = tmp / 40;               // row = b*S + s
    float c = cs[r * HDIM + d];
    float s = sn[r * HDIM + d];
    unsigned short* p = qkv + r * N_QKV + (size_t)hd * HDIM + d;
    float x1 = bf2f(p[0]), x2 = bf2f(p[64]);
    float o1 = x1 * c - x2 * s;
    float o2 = x2 * c + x1 * s;
    if (hd < NHEADS) { o1 *= 0.088388347648318447f; o2 *= 0.088388347648318447f; }
    p[0]  = f2bf(o1);
    p[64] = f2bf(o2);
}

// ---------------- 4b. V transpose: qkv V region -> vtg[b][kvh][d][s] ----------------
__global__ void transpose_v_kernel(const unsigned short* __restrict__ qkv,
                                   unsigned short* __restrict__ vtg) {
    __shared__ unsigned short tile[64][72];
    const int bz = blockIdx.z;               // b*8 + kvh
    const int d0 = blockIdx.y * 64;
    const int s0 = blockIdx.x * 64;
    const int b  = bz >> 3, kvh = bz & 7;
    const int t = threadIdx.x;
#pragma unroll
    for (int i = 0; i < 2; i++) {
        int s  = i * 32 + (t >> 3);
        int dl = (t & 7) * 8;
        bf16x8 v = *(const bf16x8*)(qkv + (size_t)(b * S_LEN + s0 + s) * N_QKV
                                    + HID + NKVH * HDIM + (size_t)kvh * HDIM + d0 + dl);
        *(bf16x8*)(&tile[s][dl]) = v;
    }
    __syncthreads();
#pragma unroll
    for (int i = 0; i < 2; i++) {
        int d  = i * 32 + (t >> 3);
        int sl = (t & 7) * 8;
        bf16x8 o;
#pragma unroll
        for (int j = 0; j < 8; j++) o[j] = (short)tile[sl + j][d];
        *(bf16x8*)(vtg + ((size_t)bz * HDIM + d0 + d) * S_LEN + s0 + sl) = o;
    }
}

// ---------------- 5. causal GQA flash attention (paired q-blocks for balance) ----------------
__global__ __launch_bounds__(256, 2) void attn_kernel(const unsigned short* __restrict__ qkv,
                                                      const unsigned short* __restrict__ vtg,
                                                      float* __restrict__ out) {
    __shared__ unsigned short Kl[2][KVBLK * HDIM];   // double-buffered, chunk-swizzled
    __shared__ unsigned short Vl[HDIM * KVBLK];      // V^T [d][kv], chunk-swizzled
    __shared__ unsigned short Pl[4][16 * 72];        // per-wave P roundtrip

    const int bid = blockIdx.x;
    const int qbi0 = bid & 7;
    const int h   = (bid >> 3) & 31;
    const int b   = bid >> 8;
    const int kvh = h >> 2;                           // GROUPS = 4
    const int t = threadIdx.x, w = t >> 6, l = t & 63;
    const int lo = l & 15, hi = l >> 4;
    const int sw = lo & 7;
    const size_t rowb = (size_t)b * S_LEN;

    const int krow = t >> 4;
    const unsigned short* kg = qkv + (rowb + krow) * N_QKV + HID + (size_t)kvh * HDIM
                               + (((t & 15) ^ (krow & 7)) << 3);
    const int vrow = t >> 3;
    const unsigned short* vg = vtg + ((size_t)(b * NKVH + kvh) * HDIM + vrow) * S_LEN
                               + (((t & 7) ^ (vrow & 7)) << 3);
    unsigned short* kl0 = &Kl[0][t * 8];
    unsigned short* kl1 = &Kl[1][t * 8];
    unsigned short* vl  = &Vl[t * 8];

    for (int hv = 0; hv < 2; hv++) {
        const int qb = (hv ? (15 - qbi0) : qbi0) * QBLK;

        // Q fragments (post-RoPE, scale folded): 2 q-groups x 4 k-chunks
        bf16x8 qf[2][4];
#pragma unroll
        for (int g = 0; g < 2; g++) {
            const unsigned short* qp = qkv + (rowb + qb + w * 32 + g * 16 + lo) * N_QKV
                                       + (size_t)h * HDIM + hi * 8;
#pragma unroll
            for (int kc = 0; kc < 4; kc++) qf[g][kc] = *(const bf16x8*)(qp + kc * 32);
        }

        f32x4 of[2][8] = {};
        float m_r[2][4], l_r[2][4];
#pragma unroll
        for (int g = 0; g < 2; g++)
#pragma unroll
            for (int r = 0; r < 4; r++) { m_r[g][r] = -1e30f; l_r[g][r] = 0.f; }

        const int nt = (qb + QBLK) / KVBLK;          // always even
        const int wrowmax = qb + w * 32 + 31;

        // prologue: stage K tile 0 (into Kl[0]; prior half ended reading Kl[1])
#pragma unroll
        for (int i = 0; i < 4; i++)
            gload_lds16(kg + (size_t)i * 16 * N_QKV, kl0 + i * 2048);

        for (int kt = 0; kt < nt; kt++) {
            const int kv0 = kt * KVBLK;
            __syncthreads();                          // K(kt) landed; prior Vl reads done
#pragma unroll
            for (int i = 0; i < 4; i++)
                gload_lds16(vg + kv0 + (size_t)i * 32 * S_LEN, vl + i * 2048);
            if (kt + 1 < nt) {
                const unsigned short* kp = kg + (size_t)(kv0 + KVBLK) * N_QKV;
                unsigned short* kd = ((kt + 1) & 1) ? kl1 : kl0;
#pragma unroll
                for (int i = 0; i < 4; i++)
                    gload_lds16(kp + (size_t)i * 16 * N_QKV, kd + i * 2048);
            }

            bf16x8 pf[2][2];
            const bool wact = (kv0 <= wrowmax);
            if (wact) {
                const unsigned short* Kb = (kt & 1) ? &Kl[1][0] : &Kl[0][0];
                f32x4 sf[2][4] = {};
#pragma unroll
                for (int kvb = 0; kvb < 4; kvb++)
#pragma unroll
                    for (int kc = 0; kc < 4; kc++) {
                        bf16x8 kf = *(const bf16x8*)(Kb + (kvb * 16 + lo) * HDIM
                                                     + (((kc * 4 + hi) ^ sw) << 3));
#pragma unroll
                        for (int g = 0; g < 2; g++)
                            sf[g][kvb] = __builtin_amdgcn_mfma_f32_16x16x32_bf16(
                                qf[g][kc], kf, sf[g][kvb], 0, 0, 0);
                    }
#pragma unroll
                for (int g = 0; g < 2; g++) {
                    const int rb = qb + w * 32 + g * 16;
                    if (kv0 + KVBLK - 1 > rb) {
#pragma unroll
                        for (int kvb = 0; kvb < 4; kvb++) {
                            const int kv = kv0 + kvb * 16 + lo;
#pragma unroll
                            for (int r = 0; r < 4; r++)
                                if (kv > rb + hi * 4 + r) sf[g][kvb][r] = -1e30f;
                        }
                    }
                    float pm[4];
#pragma unroll
                    for (int r = 0; r < 4; r++)
                        pm[r] = fmaxf(fmaxf(sf[g][0][r], sf[g][1][r]),
                                      fmaxf(sf[g][2][r], sf[g][3][r]));
#pragma unroll
                    for (int off = 8; off >= 1; off >>= 1)
#pragma unroll
                        for (int r = 0; r < 4; r++)
                            pm[r] = fmaxf(pm[r], __shfl_xor(pm[r], off, 64));
                    float dm = fmaxf(fmaxf(pm[0] - m_r[g][0], pm[1] - m_r[g][1]),
                                     fmaxf(pm[2] - m_r[g][2], pm[3] - m_r[g][3]));
                    if (__any(dm > 8.0f)) {
#pragma unroll
                        for (int r = 0; r < 4; r++) {
                            const float mn = fmaxf(m_r[g][r], pm[r]);
                            const float sc = __expf(m_r[g][r] - mn);
                            m_r[g][r] = mn;
                            l_r[g][r] *= sc;
#pragma unroll
                            for (int d16 = 0; d16 < 8; d16++) of[g][d16][r] *= sc;
                        }
                    }
                    float rs[4] = {0.f, 0.f, 0.f, 0.f};
#pragma unroll
                    for (int kvb = 0; kvb < 4; kvb++)
#pragma unroll
                        for (int r = 0; r < 4; r++) {
                            const float p = __expf(sf[g][kvb][r] - m_r[g][r]);
                            sf[g][kvb][r] = p;
                            rs[r] += p;
                        }
#pragma unroll
                    for (int off = 8; off >= 1; off >>= 1)
#pragma unroll
                        for (int r = 0; r < 4; r++) rs[r] += __shfl_xor(rs[r], off, 64);
#pragma unroll
                    for (int r = 0; r < 4; r++) l_r[g][r] += rs[r];
                    unsigned short* Pw = &Pl[w][0];
#pragma unroll
                    for (int kvb = 0; kvb < 4; kvb++)
#pragma unroll
                        for (int r = 0; r < 4; r++)
                            Pw[(hi * 4 + r) * 72 + kvb * 16 + lo] = f2bf(sf[g][kvb][r]);
#pragma unroll
                    for (int kh = 0; kh < 2; kh++)
                        pf[g][kh] = *(const bf16x8*)(Pw + lo * 72 + kh * 32 + hi * 8);
                }
            }
            __syncthreads();                          // V(kt) landed
            if (wact) {
#pragma unroll
                for (int kh = 0; kh < 2; kh++)
#pragma unroll
                    for (int d16 = 0; d16 < 8; d16++) {
                        bf16x8 vf = *(const bf16x8*)(&Vl[0]
                                                     + ((d16 * 16 + lo) << 6)
                                                     + (((kh * 4 + hi) ^ sw) << 3));
#pragma unroll
                        for (int g = 0; g < 2; g++)
                            of[g][d16] = __builtin_amdgcn_mfma_f32_16x16x32_bf16(
                                pf[g][kh], vf, of[g][d16], 0, 0, 0);
                    }
            }
        }

#pragma unroll
        for (int g = 0; g < 2; g++) {
            float inv[4];
#pragma unroll
            for (int r = 0; r < 4; r++) inv[r] = 1.0f / l_r[g][r];
            const size_t rb = rowb + qb + w * 32 + g * 16 + hi * 4;
#pragma unroll
            for (int d16 = 0; d16 < 8; d16++)
#pragma unroll
                for (int r = 0; r < 4; r++)
                    out[(rb + r) * HID + (size_t)h * HDIM + d16 * 16 + lo] = of[g][d16][r] * inv[r];
        }
    }
}

extern "C" void kernel_launch(void* const* d_in, const int* in_sizes, int n_in,
                              void* d_out, int out_size, void* d_ws, size_t ws_size,
                              hipStream_t stream) {
    const float* hidden = (const float*)d_in[0];
    const float* cosb   = (const float*)d_in[1];
    const float* sinb   = (const float*)d_in[2];
    const float* w_qkv  = (const float*)d_in[3];

    unsigned short* hbf = (unsigned short*)d_ws;                   // 32 MiB (dead after GEMM)
    unsigned short* wt  = hbf + (size_t)MROWS * HID;               // 48 MiB
    unsigned short* qkv = wt + (size_t)N_QKV * HID;                // 48 MiB
    unsigned short* vtg = (unsigned short*)d_ws;                   // 8 MiB, overlaps hbf (post-GEMM)
    float* out = (float*)d_out;

    cvt_bf16_kernel<<<(MROWS * (size_t)HID) / 1024, 256, 0, stream>>>(hidden, hbf);
    transpose_w_kernel<<<dim3(N_QKV / 64, HID / 64), 256, 0, stream>>>(w_qkv, wt);
    gemm_qkv_kernel<<<(MROWS / 128) * (N_QKV / 256), 512, 0, stream>>>(hbf, wt, qkv);
    rope_kernel<<<((size_t)MROWS * 40 * 64) / 256, 256, 0, stream>>>(qkv, cosb, sinb);
    transpose_v_kernel<<<dim3(S_LEN / 64, HDIM / 64, BATCH * NKVH), 256, 0, stream>>>(qkv, vtg);
    attn_kernel<<<BATCH * NHEADS * (S_LEN / QBLK / 2), 256, 0, stream>>>(qkv, vtg, out);
}

// Round 5
// 578.995 us; speedup vs baseline: 1.5107x; 1.0514x over previous
//
#include <hip/hip_runtime.h>
#include <hip/hip_bf16.h>

#define BATCH 2
#define S_LEN 2048
#define HID   4096
#define N_QKV 6144   // (32 + 2*8) * 128
#define NHEADS 32
#define NKVH   8
#define HDIM   128
#define MROWS  4096  // BATCH * S_LEN
#define QBLK  128
#define KVBLK 64
#define NT_K  64     // 4096 / 64 K-tiles for the GEMM

typedef __attribute__((ext_vector_type(4))) float f32x4;
typedef __attribute__((ext_vector_type(8))) short bf16x8;
typedef __attribute__((ext_vector_type(4))) short bf16x4;

__device__ __forceinline__ unsigned short f2bf(float f) {
    unsigned int u = __float_as_uint(f);
    u += 0x7FFFu + ((u >> 16) & 1u);   // round-to-nearest-even
    return (unsigned short)(u >> 16);
}
__device__ __forceinline__ float bf2f(unsigned short v) {
    return __uint_as_float(((unsigned int)v) << 16);
}

// ---------------- 1. hidden fp32 -> bf16 ----------------
__global__ void cvt_bf16_kernel(const float* __restrict__ in, unsigned short* __restrict__ out) {
    size_t i = ((size_t)blockIdx.x * 256 + threadIdx.x) * 4;
    f32x4 v = *(const f32x4*)(in + i);
    bf16x4 o;
    o.x = (short)f2bf(v.x); o.y = (short)f2bf(v.y);
    o.z = (short)f2bf(v.z); o.w = (short)f2bf(v.w);
    *(bf16x4*)(out + i) = o;
}

// ---------------- 2. w_qkv (K x N fp32) -> w^T (N x K bf16) ----------------
__global__ void transpose_w_kernel(const float* __restrict__ w, unsigned short* __restrict__ wt) {
    __shared__ unsigned short tile[64][72];   // [k][n], padded
    const int tn = blockIdx.x * 64;
    const int tk = blockIdx.y * 64;
    const int t  = threadIdx.x;
    const int c4 = (t & 15) * 4;
    const int rr = t >> 4;                    // 0..15
#pragma unroll
    for (int i = 0; i < 4; i++) {
        int k = rr + i * 16;
        f32x4 v = *(const f32x4*)(w + (size_t)(tk + k) * N_QKV + tn + c4);
        tile[k][c4 + 0] = f2bf(v.x);
        tile[k][c4 + 1] = f2bf(v.y);
        tile[k][c4 + 2] = f2bf(v.z);
        tile[k][c4 + 3] = f2bf(v.w);
    }
    __syncthreads();
#pragma unroll
    for (int i = 0; i < 4; i++) {
        int n = rr + i * 16;
        bf16x4 o;
        o.x = (short)tile[c4 + 0][n];
        o.y = (short)tile[c4 + 1][n];
        o.z = (short)tile[c4 + 2][n];
        o.w = (short)tile[c4 + 3][n];
        *(bf16x4*)(wt + (size_t)(tn + n) * HID + tk + c4) = o;
    }
}

// ---------------- async global -> LDS ----------------
__device__ __forceinline__ void gload_lds16(const unsigned short* g, unsigned short* l) {
    __builtin_amdgcn_global_load_lds(
        (const __attribute__((address_space(1))) unsigned int*)g,
        (__attribute__((address_space(3))) unsigned int*)l, 16, 0, 0);
}

// ---------------- 3. bf16 GEMM, 128x384 tile, BK=64, counted-vmcnt phases ----------------
// grid = 32 x 16 = 512 blocks = exactly 2 full rounds of 256 CUs.
// 8 waves, wave tile 64x96 -> 10 ds_read_b128 per 24 MFMA per phase (LDS pipe 17% slack).
// LDS: AL [2 dbuf][2 kh][128][32] (32 KiB), BL [2 dbuf][2 kh][384][32] (96 KiB).
// 16B-chunk XOR swizzle chunk^= (row>>1)&3, inverse baked into global staging address.
__global__ __launch_bounds__(512, 2) void gemm_qkv_kernel(const unsigned short* __restrict__ A,
                                                          const unsigned short* __restrict__ Bt,
                                                          unsigned short* __restrict__ C) {
    __shared__ alignas(16) unsigned short AL[16384];   // 32 KiB
    __shared__ alignas(16) unsigned short BL[49152];   // 96 KiB
    const int t = threadIdx.x;            // 0..511
    const int w = t >> 6, l = t & 63;
    const int lo = l & 15, hi = l >> 4;
    const int wr = w >> 2, wc = w & 3;    // wave tile 64x96 at (wr*64, wc*96)
    // XCD-grouped: each XCD owns 64 consecutive g = 2 bn-columns x 32 bm
    // (3 MB B-panel stays hot in that XCD's 4 MB L2).
    const int bid = blockIdx.x;
    const int g = (bid & 7) * 64 + (bid >> 3);         // bijective, 512 = 8*64
    const int bm = (g & 31) * 128;
    const int bn = (g >> 5) * 384;

    const int rS = t >> 2;                              // staging row 0..127
    const int cS = (t & 3) ^ ((rS >> 1) & 3);           // pre-swizzled 16B chunk
    const unsigned short* As = A  + (size_t)(bm + rS) * HID + cS * 8;
    const unsigned short* Bs = Bt + (size_t)(bn + rS) * HID + cS * 8;

#define STAGE_A(DB, KH, KPOS) gload_lds16(As + (KPOS), AL + (DB) * 8192 + (KH) * 4096 + t * 8)
#define STAGE_B(DB, KH, KPOS) do { \
        unsigned short* _d = BL + (DB) * 24576 + (KH) * 12288 + t * 8; \
        gload_lds16(Bs + (KPOS), _d); \
        gload_lds16(Bs + (size_t)128 * HID + (KPOS), _d + 4096); \
        gload_lds16(Bs + (size_t)256 * HID + (KPOS), _d + 8192); } while (0)

    // prologue: T0.k0, T0.k1, T1.k0 (4 loads/thread each -> 12 in flight)
    STAGE_A(0, 0, 0);   STAGE_B(0, 0, 0);
    STAGE_A(0, 1, 32);  STAGE_B(0, 1, 32);
    STAGE_A(1, 0, 64);  STAGE_B(1, 0, 64);
    asm volatile("s_waitcnt vmcnt(8)" ::: "memory");    // T0.k0 landed
    __builtin_amdgcn_s_barrier();

    f32x4 acc[4][6] = {};
    const int csw8 = (hi ^ ((l & 6) >> 1)) * 8;         // swizzled chunk offset (ushorts)

#define GPHASE(U, KH, STAGECODE, WAITCODE) do {                                  \
        const unsigned short* ap = AL + ((U) & 1) * 8192 + (KH) * 4096           \
                                   + (wr * 64 + lo) * 32 + csw8;                 \
        const unsigned short* bp = BL + ((U) & 1) * 24576 + (KH) * 12288         \
                                   + (wc * 96 + lo) * 32 + csw8;                 \
        bf16x8 af[4], bfv[6];                                                    \
        _Pragma("unroll")                                                        \
        for (int i = 0; i < 4; i++) af[i] = *(const bf16x8*)(ap + i * 512);      \
        _Pragma("unroll")                                                        \
        for (int j = 0; j < 6; j++) bfv[j] = *(const bf16x8*)(bp + j * 512);     \
        STAGECODE;                                                               \
        __builtin_amdgcn_s_barrier();                                            \
        __builtin_amdgcn_s_setprio(1);                                           \
        _Pragma("unroll")                                                        \
        for (int i = 0; i < 4; i++)                                              \
        _Pragma("unroll")                                                        \
        for (int j = 0; j < 6; j++)                                              \
            acc[i][j] = __builtin_amdgcn_mfma_f32_16x16x32_bf16(af[i], bfv[j], acc[i][j], 0, 0, 0); \
        __builtin_amdgcn_s_setprio(0);                                           \
        WAITCODE;                                                                \
        __builtin_amdgcn_s_barrier();                                            \
    } while (0)

    // In-flight ledger (4 loads per staged half-group, in-order completion):
    //  entry tile u: {T(u).k1, T(u+1).k0} = 8 outstanding
    //  P1: +T(u+1).k1 -> 12; wait 8 drains T(u).k1
    //  P2: +T(u+2).k0 -> 12; wait 8 drains T(u+1).k0
    for (int u = 0; u < NT_K; u++) {
        GPHASE(u, 0,
               { if (u + 1 < NT_K) { STAGE_A((u + 1) & 1, 1, (u + 1) * 64 + 32);
                                     STAGE_B((u + 1) & 1, 1, (u + 1) * 64 + 32); } },
               { if (u < NT_K - 1) asm volatile("s_waitcnt vmcnt(8)" ::: "memory");
                 else              asm volatile("s_waitcnt vmcnt(0)" ::: "memory"); });
        GPHASE(u, 1,
               { if (u + 2 < NT_K) { STAGE_A(u & 1, 0, (u + 2) * 64);
                                     STAGE_B(u & 1, 0, (u + 2) * 64); } },
               { if (u < NT_K - 2)       asm volatile("s_waitcnt vmcnt(8)" ::: "memory");
                 else if (u == NT_K - 2) asm volatile("s_waitcnt vmcnt(4)" ::: "memory"); });
    }
#undef GPHASE
#undef STAGE_A
#undef STAGE_B

#pragma unroll
    for (int i = 0; i < 4; i++)
#pragma unroll
        for (int j = 0; j < 6; j++)
#pragma unroll
            for (int r = 0; r < 4; r++) {
                const int row = bm + wr * 64 + i * 16 + hi * 4 + r;
                const int col = bn + wc * 96 + j * 16 + lo;
                C[(size_t)row * N_QKV + col] = f2bf(acc[i][j][r]);
            }
}

// ---------------- 4. RoPE in-place on Q/K regions (+ fold 1/sqrt(HD) into Q) ----------------
__global__ void rope_kernel(unsigned short* __restrict__ qkv,
                            const float* __restrict__ cs, const float* __restrict__ sn) {
    size_t id = (size_t)blockIdx.x * 256 + threadIdx.x;
    int d = (int)(id & 63);
    size_t tmp = id >> 6;
    int hd = (int)(tmp % 40);          // 0..31 = Q heads, 32..39 = K heads
    size_t r = tmp / 40;               // row = b*S + s
    float c = cs[r * HDIM + d];
    float s = sn[r * HDIM + d];
    unsigned short* p = qkv + r * N_QKV + (size_t)hd * HDIM + d;
    float x1 = bf2f(p[0]), x2 = bf2f(p[64]);
    float o1 = x1 * c - x2 * s;
    float o2 = x2 * c + x1 * s;
    if (hd < NHEADS) { o1 *= 0.088388347648318447f; o2 *= 0.088388347648318447f; }
    p[0]  = f2bf(o1);
    p[64] = f2bf(o2);
}

// ---------------- 4b. V transpose: qkv V region -> vtg[b][kvh][d][s] ----------------
__global__ void transpose_v_kernel(const unsigned short* __restrict__ qkv,
                                   unsigned short* __restrict__ vtg) {
    __shared__ unsigned short tile[64][72];
    const int bz = blockIdx.z;               // b*8 + kvh
    const int d0 = blockIdx.y * 64;
    const int s0 = blockIdx.x * 64;
    const int b  = bz >> 3, kvh = bz & 7;
    const int t = threadIdx.x;
#pragma unroll
    for (int i = 0; i < 2; i++) {
        int s  = i * 32 + (t >> 3);
        int dl = (t & 7) * 8;
        bf16x8 v = *(const bf16x8*)(qkv + (size_t)(b * S_LEN + s0 + s) * N_QKV
                                    + HID + NKVH * HDIM + (size_t)kvh * HDIM + d0 + dl);
        *(bf16x8*)(&tile[s][dl]) = v;
    }
    __syncthreads();
#pragma unroll
    for (int i = 0; i < 2; i++) {
        int d  = i * 32 + (t >> 3);
        int sl = (t & 7) * 8;
        bf16x8 o;
#pragma unroll
        for (int j = 0; j < 8; j++) o[j] = (short)tile[sl + j][d];
        *(bf16x8*)(vtg + ((size_t)bz * HDIM + d0 + d) * S_LEN + s0 + sl) = o;
    }
}

// ---------------- 5. causal GQA flash attention (paired q-blocks for balance) ----------------
__global__ __launch_bounds__(256, 2) void attn_kernel(const unsigned short* __restrict__ qkv,
                                                      const unsigned short* __restrict__ vtg,
                                                      float* __restrict__ out) {
    __shared__ unsigned short Kl[2][KVBLK * HDIM];   // double-buffered, chunk-swizzled
    __shared__ unsigned short Vl[HDIM * KVBLK];      // V^T [d][kv], chunk-swizzled
    __shared__ unsigned short Pl[4][16 * 72];        // per-wave P roundtrip

    const int bid = blockIdx.x;
    const int qbi0 = bid & 7;
    const int h   = (bid >> 3) & 31;
    const int b   = bid >> 8;
    const int kvh = h >> 2;                           // GROUPS = 4
    const int t = threadIdx.x, w = t >> 6, l = t & 63;
    const int lo = l & 15, hi = l >> 4;
    const int sw = lo & 7;
    const size_t rowb = (size_t)b * S_LEN;

    const int krow = t >> 4;
    const unsigned short* kg = qkv + (rowb + krow) * N_QKV + HID + (size_t)kvh * HDIM
                               + (((t & 15) ^ (krow & 7)) << 3);
    const int vrow = t >> 3;
    const unsigned short* vg = vtg + ((size_t)(b * NKVH + kvh) * HDIM + vrow) * S_LEN
                               + (((t & 7) ^ (vrow & 7)) << 3);
    unsigned short* kl0 = &Kl[0][t * 8];
    unsigned short* kl1 = &Kl[1][t * 8];
    unsigned short* vl  = &Vl[t * 8];

    for (int hv = 0; hv < 2; hv++) {
        const int qb = (hv ? (15 - qbi0) : qbi0) * QBLK;

        // Q fragments (post-RoPE, scale folded): 2 q-groups x 4 k-chunks
        bf16x8 qf[2][4];
#pragma unroll
        for (int g = 0; g < 2; g++) {
            const unsigned short* qp = qkv + (rowb + qb + w * 32 + g * 16 + lo) * N_QKV
                                       + (size_t)h * HDIM + hi * 8;
#pragma unroll
            for (int kc = 0; kc < 4; kc++) qf[g][kc] = *(const bf16x8*)(qp + kc * 32);
        }

        f32x4 of[2][8] = {};
        float m_r[2][4], l_r[2][4];
#pragma unroll
        for (int g = 0; g < 2; g++)
#pragma unroll
            for (int r = 0; r < 4; r++) { m_r[g][r] = -1e30f; l_r[g][r] = 0.f; }

        const int nt = (qb + QBLK) / KVBLK;          // always even
        const int wrowmax = qb + w * 32 + 31;

        // prologue: stage K tile 0 (into Kl[0]; prior half ended reading Kl[1])
#pragma unroll
        for (int i = 0; i < 4; i++)
            gload_lds16(kg + (size_t)i * 16 * N_QKV, kl0 + i * 2048);

        for (int kt = 0; kt < nt; kt++) {
            const int kv0 = kt * KVBLK;
            __syncthreads();                          // K(kt) landed; prior Vl reads done
#pragma unroll
            for (int i = 0; i < 4; i++)
                gload_lds16(vg + kv0 + (size_t)i * 32 * S_LEN, vl + i * 2048);
            if (kt + 1 < nt) {
                const unsigned short* kp = kg + (size_t)(kv0 + KVBLK) * N_QKV;
                unsigned short* kd = ((kt + 1) & 1) ? kl1 : kl0;
#pragma unroll
                for (int i = 0; i < 4; i++)
                    gload_lds16(kp + (size_t)i * 16 * N_QKV, kd + i * 2048);
            }

            bf16x8 pf[2][2];
            const bool wact = (kv0 <= wrowmax);
            if (wact) {
                const unsigned short* Kb = (kt & 1) ? &Kl[1][0] : &Kl[0][0];
                f32x4 sf[2][4] = {};
#pragma unroll
                for (int kvb = 0; kvb < 4; kvb++)
#pragma unroll
                    for (int kc = 0; kc < 4; kc++) {
                        bf16x8 kf = *(const bf16x8*)(Kb + (kvb * 16 + lo) * HDIM
                                                     + (((kc * 4 + hi) ^ sw) << 3));
#pragma unroll
                        for (int g = 0; g < 2; g++)
                            sf[g][kvb] = __builtin_amdgcn_mfma_f32_16x16x32_bf16(
                                qf[g][kc], kf, sf[g][kvb], 0, 0, 0);
                    }
#pragma unroll
                for (int g = 0; g < 2; g++) {
                    const int rb = qb + w * 32 + g * 16;
                    if (kv0 + KVBLK - 1 > rb) {
#pragma unroll
                        for (int kvb = 0; kvb < 4; kvb++) {
                            const int kv = kv0 + kvb * 16 + lo;
#pragma unroll
                            for (int r = 0; r < 4; r++)
                                if (kv > rb + hi * 4 + r) sf[g][kvb][r] = -1e30f;
                        }
                    }
                    float pm[4];
#pragma unroll
                    for (int r = 0; r < 4; r++)
                        pm[r] = fmaxf(fmaxf(sf[g][0][r], sf[g][1][r]),
                                      fmaxf(sf[g][2][r], sf[g][3][r]));
#pragma unroll
                    for (int off = 8; off >= 1; off >>= 1)
#pragma unroll
                        for (int r = 0; r < 4; r++)
                            pm[r] = fmaxf(pm[r], __shfl_xor(pm[r], off, 64));
                    float dm = fmaxf(fmaxf(pm[0] - m_r[g][0], pm[1] - m_r[g][1]),
                                     fmaxf(pm[2] - m_r[g][2], pm[3] - m_r[g][3]));
                    if (__any(dm > 8.0f)) {
#pragma unroll
                        for (int r = 0; r < 4; r++) {
                            const float mn = fmaxf(m_r[g][r], pm[r]);
                            const float sc = __expf(m_r[g][r] - mn);
                            m_r[g][r] = mn;
                            l_r[g][r] *= sc;
#pragma unroll
                            for (int d16 = 0; d16 < 8; d16++) of[g][d16][r] *= sc;
                        }
                    }
                    float rs[4] = {0.f, 0.f, 0.f, 0.f};
#pragma unroll
                    for (int kvb = 0; kvb < 4; kvb++)
#pragma unroll
                        for (int r = 0; r < 4; r++) {
                            const float p = __expf(sf[g][kvb][r] - m_r[g][r]);
                            sf[g][kvb][r] = p;
                            rs[r] += p;
                        }
#pragma unroll
                    for (int off = 8; off >= 1; off >>= 1)
#pragma unroll
                        for (int r = 0; r < 4; r++) rs[r] += __shfl_xor(rs[r], off, 64);
#pragma unroll
                    for (int r = 0; r < 4; r++) l_r[g][r] += rs[r];
                    unsigned short* Pw = &Pl[w][0];
#pragma unroll
                    for (int kvb = 0; kvb < 4; kvb++)
#pragma unroll
                        for (int r = 0; r < 4; r++)
                            Pw[(hi * 4 + r) * 72 + kvb * 16 + lo] = f2bf(sf[g][kvb][r]);
#pragma unroll
                    for (int kh = 0; kh < 2; kh++)
                        pf[g][kh] = *(const bf16x8*)(Pw + lo * 72 + kh * 32 + hi * 8);
                }
            }
            __syncthreads();                          // V(kt) landed
            if (wact) {
#pragma unroll
                for (int kh = 0; kh < 2; kh++)
#pragma unroll
                    for (int d16 = 0; d16 < 8; d16++) {
                        bf16x8 vf = *(const bf16x8*)(&Vl[0]
                                                     + ((d16 * 16 + lo) << 6)
                                                     + (((kh * 4 + hi) ^ sw) << 3));
#pragma unroll
                        for (int g = 0; g < 2; g++)
                            of[g][d16] = __builtin_amdgcn_mfma_f32_16x16x32_bf16(
                                pf[g][kh], vf, of[g][d16], 0, 0, 0);
                    }
            }
        }

#pragma unroll
        for (int g = 0; g < 2; g++) {
            float inv[4];
#pragma unroll
            for (int r = 0; r < 4; r++) inv[r] = 1.0f / l_r[g][r];
            const size_t rb = rowb + qb + w * 32 + g * 16 + hi * 4;
#pragma unroll
            for (int d16 = 0; d16 < 8; d16++)
#pragma unroll
                for (int r = 0; r < 4; r++)
                    out[(rb + r) * HID + (size_t)h * HDIM + d16 * 16 + lo] = of[g][d16][r] * inv[r];
        }
    }
}

extern "C" void kernel_launch(void* const* d_in, const int* in_sizes, int n_in,
                              void* d_out, int out_size, void* d_ws, size_t ws_size,
                              hipStream_t stream) {
    const float* hidden = (const float*)d_in[0];
    const float* cosb   = (const float*)d_in[1];
    const float* sinb   = (const float*)d_in[2];
    const float* w_qkv  = (const float*)d_in[3];

    unsigned short* hbf = (unsigned short*)d_ws;                   // 32 MiB (dead after GEMM)
    unsigned short* wt  = hbf + (size_t)MROWS * HID;               // 48 MiB
    unsigned short* qkv = wt + (size_t)N_QKV * HID;                // 48 MiB
    unsigned short* vtg = (unsigned short*)d_ws;                   // 8 MiB, overlaps hbf (post-GEMM)
    float* out = (float*)d_out;

    cvt_bf16_kernel<<<(MROWS * (size_t)HID) / 1024, 256, 0, stream>>>(hidden, hbf);
    transpose_w_kernel<<<dim3(N_QKV / 64, HID / 64), 256, 0, stream>>>(w_qkv, wt);
    gemm_qkv_kernel<<<(MROWS / 128) * (N_QKV / 384), 512, 0, stream>>>(hbf, wt, qkv);
    rope_kernel<<<((size_t)MROWS * 40 * 64) / 256, 256, 0, stream>>>(qkv, cosb, sinb);
    transpose_v_kernel<<<dim3(S_LEN / 64, HDIM / 64, BATCH * NKVH), 256, 0, stream>>>(qkv, vtg);
    attn_kernel<<<BATCH * NHEADS * (S_LEN / QBLK / 2), 256, 0, stream>>>(qkv, vtg, out);
}